// Round 10
// baseline (3301.366 us; speedup 1.0000x reference)
//
#include <hip/hip_runtime.h>

#define N_NODES 50000
#define E_ADJ   800000
#define E_DEC   200000
#define FDIM    128
#define HDIM    64
#define NP1     (N_NODES + 1)
#define NBUK    196            // ceil(50000/256) buckets of 256 rows
#define BCAP    5120           // bucket capacity; mean 4082, sigma~64 -> 16-sigma margin

__device__ __forceinline__ int   ntl_i(const int* p)   { return __builtin_nontemporal_load(p); }
__device__ __forceinline__ float ntl_f(const float* p) { return __builtin_nontemporal_load(p); }

// ---------------------------------------------------------------------------
// CSR build, two-level bucket sort.
// P1: partition edges into 256-row buckets. 8B payload {col16|rowlocal8, val}.
// Active write set = 784 bucket tails (~50KB) -> L2-resident, no 64B-line
// write amplification (R8/R9 lesson: single-pass random scatter over 25.6MB
// structurally writes ~205MB; bucketing localizes the randomness).
// ---------------------------------------------------------------------------
__global__ void part_kernel(const int* __restrict__ rows,
                            const int* __restrict__ cols,
                            const float* __restrict__ vals,
                            int* __restrict__ gcur,
                            unsigned long long* __restrict__ bucketed)
{
    const int k = blockIdx.y;
    const int e = blockIdx.x * 256 + threadIdx.x;   // 3125*256 == E_ADJ exactly
    const int r = ntl_i(&rows[(size_t)k * E_ADJ + e]);
    const int c = ntl_i(&cols[(size_t)k * E_ADJ + e]);
    const float v = ntl_f(&vals[(size_t)k * E_ADJ + e]);

    const int b = r >> 8;                            // bucket (row / 256)
    const unsigned meta = (unsigned)c | ((unsigned)(r & 255) << 16);  // col<65536
    const unsigned long long payload =
        ((unsigned long long)__float_as_uint(v) << 32) | meta;
    const int pos = atomicAdd(&gcur[k * NBUK + b], 1);
    bucketed[((size_t)(k * NBUK + b)) * BCAP + pos] = payload;
}

// P2: per-relation exclusive scan of bucket counts -> srt base per bucket.
__global__ void bucket_scan(const int* __restrict__ gcur, int* __restrict__ srtbase)
{
    const int k = threadIdx.x;
    if (k < 4) {
        int run = 0;
        for (int b = 0; b < NBUK; ++b) {
            srtbase[k * NBUK + b] = run;
            run += gcur[k * NBUK + b];
        }
    }
}

// P3: per-bucket row sort. LDS row-hist + scan -> row_ptr; scatter to final
// srt positions (random 8B but within a ~40KB window -> L2-absorbed).
__global__ void bucket_sort(const unsigned long long* __restrict__ bucketed,
                            const int* __restrict__ gcur,
                            const int* __restrict__ srtbase,
                            float2* __restrict__ srt,
                            int* __restrict__ row_ptr)
{
    const int b = blockIdx.x, k = blockIdx.y, tid = threadIdx.x;
    const int cnt  = gcur[k * NBUK + b];
    const int base = srtbase[k * NBUK + b];
    const unsigned long long* bk = bucketed + (size_t)(k * NBUK + b) * BCAP;

    __shared__ int s[256];
    __shared__ int cur[256];
    __shared__ int rcnt[256];
    rcnt[tid] = 0;
    __syncthreads();

    for (int i = tid; i < cnt; i += 256) {
        const unsigned meta = (unsigned)bk[i];
        atomicAdd(&rcnt[(meta >> 16) & 255], 1);
    }
    __syncthreads();

    const int v = rcnt[tid];
    s[tid] = v;
    __syncthreads();
    for (int off = 1; off < 256; off <<= 1) {
        const int t = (tid >= off) ? s[tid - off] : 0;
        __syncthreads();
        s[tid] += t;
        __syncthreads();
    }
    const int excl = s[tid] - v;

    const int n = b * 256 + tid;
    if (n < N_NODES) row_ptr[k * NP1 + n] = base + excl;
    if (b == NBUK - 1 && tid == 0) row_ptr[k * NP1 + N_NODES] = E_ADJ;
    cur[tid] = base + excl;
    __syncthreads();

    for (int i = tid; i < cnt; i += 256) {
        const unsigned long long p = bk[i];
        const unsigned meta = (unsigned)p;
        const int rl = (meta >> 16) & 255;
        const int c  = meta & 0xFFFF;
        const float val = __uint_as_float((unsigned)(p >> 32));
        const int pos = atomicAdd(&cur[rl], 1);
        srt[(size_t)k * E_ADJ + pos] = make_float2(__int_as_float(c), val);
    }
}

// ---------------------------------------------------------------------------
// Stage-1 dense transform: xw[k][n][h] = sum_f xin_k[n][f] * W[k][f][h]
// ---------------------------------------------------------------------------
template <int FIN>
__global__ void gemm_stage(const float* __restrict__ x0,
                           const float* __restrict__ x1,
                           const float* __restrict__ W,   // [4][FIN][HDIM]
                           float* __restrict__ xw)        // [4][N][HDIM]
{
    const int wave = threadIdx.x >> 6;   // relation k
    const int lane = threadIdx.x & 63;   // h
    const int n0 = blockIdx.x * 8;       // 6250 blocks * 8 = 50000 exactly

    __shared__ float sx[2][8][FIN];
    for (int i = threadIdx.x; i < 8 * FIN; i += 256) {
        const int r = i / FIN, f = i % FIN;
        sx[0][r][f] = x0[(size_t)(n0 + r) * FIN + f];
        sx[1][r][f] = x1[(size_t)(n0 + r) * FIN + f];
    }
    __syncthreads();

    const float* Wk = W + (size_t)wave * FIN * HDIM;
    const float (*xr)[FIN] = sx[wave & 1];

    float acc[8] = {0.f, 0.f, 0.f, 0.f, 0.f, 0.f, 0.f, 0.f};
#pragma unroll 4
    for (int f = 0; f < FIN; ++f) {
        const float w = Wk[(size_t)f * HDIM + lane];
#pragma unroll
        for (int r = 0; r < 8; ++r)
            acc[r] = fmaf(xr[r][f], w, acc[r]);
    }

    float* outp = xw + ((size_t)wave * N_NODES + n0) * HDIM + lane;
#pragma unroll
    for (int r = 0; r < 8; ++r)
        outp[(size_t)r * HDIM] = acc[r];
}

// ---------------------------------------------------------------------------
// Stage-1 SPMM (post-transform gather) + relu + pairwise sum.
// ---------------------------------------------------------------------------
__global__ void spmm_csr(const float2* __restrict__ srt,    // [4][E] {col,val}
                         const int*    __restrict__ row_ptr,// [4][N+1]
                         const float*  __restrict__ xw,     // [4][N][H]
                         float* __restrict__ h0, float* __restrict__ h1)
{
    const int k = threadIdx.x >> 6;
    const int lane = threadIdx.x & 63;
    const int n = blockIdx.x;

    const int s  = row_ptr[k * NP1 + n];
    const int en = row_ptr[k * NP1 + n + 1];
    const float2* sp = srt + (size_t)k * E_ADJ;
    const float*  xk = xw + (size_t)k * N_NODES * HDIM;

    float a[8] = {0.f, 0.f, 0.f, 0.f, 0.f, 0.f, 0.f, 0.f};

    for (int base = s; base < en; base += 64) {
        const int cnt = min(64, en - base);
        float2 meta = make_float2(0.f, 0.f);
        if (lane < cnt) meta = sp[base + lane];   // one coalesced meta load

        int j = 0;
        for (; j + 8 <= cnt; j += 8) {
            int   c[8];
            float v[8], g[8];
#pragma unroll
            for (int u = 0; u < 8; ++u) {
                c[u] = __shfl(__float_as_int(meta.x), j + u, 64);
                v[u] = __shfl(meta.y, j + u, 64);
            }
#pragma unroll
            for (int u = 0; u < 8; ++u)           // 8 independent gathers in flight
                g[u] = xk[(size_t)c[u] * HDIM + lane];
#pragma unroll
            for (int u = 0; u < 8; ++u)
                a[u] = fmaf(g[u], v[u], a[u]);
        }
        for (; j < cnt; ++j) {
            const int   cc = __shfl(__float_as_int(meta.x), j, 64);
            const float vv = __shfl(meta.y, j, 64);
            a[0] = fmaf(xk[(size_t)cc * HDIM + lane], vv, a[0]);
        }
    }

    float acc = ((a[0] + a[1]) + (a[2] + a[3])) + ((a[4] + a[5]) + (a[6] + a[7]));
    acc = fmaxf(acc, 0.f);

    __shared__ float sacc[4][HDIM];
    sacc[k][lane] = acc;
    __syncthreads();
    if (k == 0)      h0[(size_t)n * HDIM + lane] = sacc[0][lane] + sacc[1][lane];
    else if (k == 1) h1[(size_t)n * HDIM + lane] = sacc[2][lane] + sacc[3][lane];
}

// ---------------------------------------------------------------------------
// Stages 2-4: aggregate-then-transform (spmm(x@W) == spmm(x)@W).
// ---------------------------------------------------------------------------
__global__ void agg_csr(const float2* __restrict__ srt,
                        const int*    __restrict__ row_ptr,
                        const float*  __restrict__ x0,
                        const float*  __restrict__ x1,
                        float* __restrict__ agg)    // [4][N][H]
{
    const int k = threadIdx.x >> 6;
    const int lane = threadIdx.x & 63;
    const int n = blockIdx.x;

    const int s  = row_ptr[k * NP1 + n];
    const int en = row_ptr[k * NP1 + n + 1];
    const float2* sp = srt + (size_t)k * E_ADJ;
    const float*  xk = (k & 1) ? x1 : x0;

    float a[8] = {0.f, 0.f, 0.f, 0.f, 0.f, 0.f, 0.f, 0.f};

    for (int base = s; base < en; base += 64) {
        const int cnt = min(64, en - base);
        float2 meta = make_float2(0.f, 0.f);
        if (lane < cnt) meta = sp[base + lane];

        int j = 0;
        for (; j + 8 <= cnt; j += 8) {
            int   c[8];
            float v[8], g[8];
#pragma unroll
            for (int u = 0; u < 8; ++u) {
                c[u] = __shfl(__float_as_int(meta.x), j + u, 64);
                v[u] = __shfl(meta.y, j + u, 64);
            }
#pragma unroll
            for (int u = 0; u < 8; ++u)
                g[u] = xk[(size_t)c[u] * HDIM + lane];
#pragma unroll
            for (int u = 0; u < 8; ++u)
                a[u] = fmaf(g[u], v[u], a[u]);
        }
        for (; j < cnt; ++j) {
            const int   cc = __shfl(__float_as_int(meta.x), j, 64);
            const float vv = __shfl(meta.y, j, 64);
            a[0] = fmaf(xk[(size_t)cc * HDIM + lane], vv, a[0]);
        }
    }

    const float acc = ((a[0] + a[1]) + (a[2] + a[3])) + ((a[4] + a[5]) + (a[6] + a[7]));
    agg[((size_t)k * N_NODES + n) * HDIM + lane] = acc;
}

// y_k = relu(agg_k @ W_k); h0 = y0+y1, h1 = y2+y3.  8 nodes/block, wave = k.
__global__ void gemm2(const float* __restrict__ agg,  // [4][N][H]
                      const float* __restrict__ W,    // [4][H][H]
                      float* __restrict__ h0, float* __restrict__ h1)
{
    const int wave = threadIdx.x >> 6;   // relation k
    const int lane = threadIdx.x & 63;   // h
    const int n0 = blockIdx.x * 8;       // 6250 blocks

    __shared__ float sg[4][8][HDIM];
    for (int i = threadIdx.x; i < 4 * 8 * HDIM; i += 256) {
        const int k = i >> 9, rem = i & 511;
        const int r = rem >> 6, f = rem & 63;
        sg[k][r][f] = agg[((size_t)k * N_NODES + n0 + r) * HDIM + f];
    }
    __syncthreads();

    const float* Wk = W + (size_t)wave * HDIM * HDIM;
    float acc[8] = {0.f, 0.f, 0.f, 0.f, 0.f, 0.f, 0.f, 0.f};
#pragma unroll 4
    for (int f = 0; f < HDIM; ++f) {
        const float w = Wk[f * HDIM + lane];
#pragma unroll
        for (int r = 0; r < 8; ++r)
            acc[r] = fmaf(sg[wave][r][f], w, acc[r]);
    }
    __syncthreads();
#pragma unroll
    for (int r = 0; r < 8; ++r)
        sg[wave][r][lane] = fmaxf(acc[r], 0.f);   // reuse LDS for relu'd y
    __syncthreads();

    if (wave == 0) {
#pragma unroll
        for (int r = 0; r < 8; ++r)
            h0[(size_t)(n0 + r) * HDIM + lane] = sg[0][r][lane] + sg[1][r][lane];
    } else if (wave == 1) {
#pragma unroll
        for (int r = 0; r < 8; ++r)
            h1[(size_t)(n0 + r) * HDIM + lane] = sg[2][r][lane] + sg[3][r][lane];
    }
}

// ---------------------------------------------------------------------------
__global__ void make_M(const float* __restrict__ R, const float* __restrict__ Dl,
                       const int* __restrict__ rt_k, float* __restrict__ M)
{
    const int i = blockIdx.x * blockDim.x + threadIdx.x;
    if (i >= HDIM * HDIM) return;
    const float* d = Dl + rt_k[0] * HDIM;
    M[i] = d[i >> 6] * R[i] * d[i & 63];
}

// A[n][g] = sum_h h0[n][h] * M[h][g]   (16 rows/block, 4 waves x 4 rows)
__global__ void h0M_kernel(const float* __restrict__ h0, const float* __restrict__ M,
                           float* __restrict__ A)
{
    const int wave = threadIdx.x >> 6, lane = threadIdx.x & 63;
    const int n0 = blockIdx.x * 16;      // 3125 blocks * 16 = 50000 exactly

    __shared__ float sx[16][HDIM];
    for (int i = threadIdx.x; i < 16 * HDIM; i += 256)
        sx[i >> 6][i & 63] = h0[(size_t)n0 * HDIM + i];
    __syncthreads();

    float acc[4] = {0.f, 0.f, 0.f, 0.f};
#pragma unroll 4
    for (int f = 0; f < HDIM; ++f) {
        const float w = M[f * HDIM + lane];
#pragma unroll
        for (int r = 0; r < 4; ++r)
            acc[r] = fmaf(sx[wave * 4 + r][f], w, acc[r]);
    }
#pragma unroll
    for (int r = 0; r < 4; ++r)
        A[(size_t)(n0 + wave * 4 + r) * HDIM + lane] = acc[r];
}

// preds[e] = dot(A[i], h1[j]) — one wave per edge, 64-wide dot + reduce.
__global__ void decode(const float* __restrict__ A, const float* __restrict__ h1,
                       const int* __restrict__ edges, float* __restrict__ out)
{
    const long long t = (long long)blockIdx.x * 256 + threadIdx.x;
    const int e = (int)(t >> 6);
    const int lane = (int)(t & 63);

    const int i = edges[2 * (size_t)e];
    const int j = edges[2 * (size_t)e + 1];

    float p = A[(size_t)i * HDIM + lane] * h1[(size_t)j * HDIM + lane];
#pragma unroll
    for (int off = 32; off; off >>= 1)
        p += __shfl_down(p, off, 64);
    if (lane == 0) out[e] = p;
}

// ---------------------------------------------------------------------------
static void build_csr(const int* rows, const int* cols, const float* vals,
                      int* gcur, int* srtbase, unsigned long long* bucketed,
                      float2* srt, int* row_ptr, hipStream_t stream)
{
    hipMemsetAsync(gcur, 0, 4 * NBUK * sizeof(int), stream);
    part_kernel<<<dim3(E_ADJ / 256, 4), 256, 0, stream>>>(rows, cols, vals, gcur, bucketed);
    bucket_scan<<<1, 64, 0, stream>>>(gcur, srtbase);
    bucket_sort<<<dim3(NBUK, 4), 256, 0, stream>>>(bucketed, gcur, srtbase, srt, row_ptr);
}

extern "C" void kernel_launch(void* const* d_in, const int* in_sizes, int n_in,
                              void* d_out, int out_size, void* d_ws, size_t ws_size,
                              hipStream_t stream) {
    const int*   adj_rows = (const int*)  d_in[0];
    const int*   adj_cols = (const int*)  d_in[1];
    const float* adj_vals = (const float*)d_in[2];
    const float* feat0    = (const float*)d_in[3];
    const float* feat1    = (const float*)d_in[4];
    const float* W1       = (const float*)d_in[5];
    const float* W2       = (const float*)d_in[6];
    const float* W3       = (const float*)d_in[7];
    const float* W4       = (const float*)d_in[8];
    const float* Rg       = (const float*)d_in[9];
    const float* Dl       = (const float*)d_in[10];
    const int*   edges    = (const int*)  d_in[11];
    const int*   rt_k     = (const int*)  d_in[12];
    float* out = (float*)d_out;

    const size_t NH = (size_t)N_NODES * HDIM;
    float* ws = (float*)d_ws;
    float*  xw      = ws;                         // 4*NH (also: bucketed alias, agg, A)
    float*  h0      = xw + 4 * NH;                // NH
    float*  h1      = h0 + NH;                    // NH
    float2* srt     = (float2*)(h1 + NH);         // 4*E float2 = 6.4M f
    int*    row_ptr = (int*)(h1 + NH + 8 * (size_t)E_ADJ); // 4*(N+1)
    int*    gcur    = row_ptr + 4 * NP1 + 60;     // 4*NBUK
    int*    srtbase = gcur + 4 * NBUK;            // 4*NBUK
    float*  M       = (float*)(srtbase + 4 * NBUK + 32); // 4096 f
    // bucketed aliases xw region: 4*196*5120*8B = 32.1MB < 51.2MB; it is dead
    // before anything writes xw (P3 of each build consumes it first).
    unsigned long long* bucketed = (unsigned long long*)xw;
    // total ~= 25.9M floats ~= 103 MB

    const int* r2 = adj_rows + 4 * (size_t)E_ADJ;
    const int* c2 = adj_cols + 4 * (size_t)E_ADJ;
    const float* v2 = adj_vals + 4 * (size_t)E_ADJ;

    // ---- CSR for adjacency group A (stages 1 & 2) ----
    build_csr(adj_rows, adj_cols, adj_vals, gcur, srtbase, bucketed, srt, row_ptr, stream);

    // ---- stage 1: transform-then-aggregate (F=128 -> gather 64-dim xw) ----
    gemm_stage<FDIM><<<N_NODES / 8, 256, 0, stream>>>(feat0, feat1, W1, xw);
    spmm_csr<<<N_NODES, 256, 0, stream>>>(srt, row_ptr, xw, h0, h1);

    // ---- stage 2: aggregate-then-transform ----
    agg_csr<<<N_NODES, 256, 0, stream>>>(srt, row_ptr, h0, h1, xw);
    gemm2<<<N_NODES / 8, 256, 0, stream>>>(xw, W2, h0, h1);

    // ---- CSR for adjacency group B (stages 3 & 4) ----
    build_csr(r2, c2, v2, gcur, srtbase, bucketed, srt, row_ptr, stream);

    // ---- stage 3 ----
    agg_csr<<<N_NODES, 256, 0, stream>>>(srt, row_ptr, h0, h1, xw);
    gemm2<<<N_NODES / 8, 256, 0, stream>>>(xw, W3, h0, h1);

    // ---- stage 4 ----
    agg_csr<<<N_NODES, 256, 0, stream>>>(srt, row_ptr, h0, h1, xw);
    gemm2<<<N_NODES / 8, 256, 0, stream>>>(xw, W4, h0, h1);

    // ---- decode: M, A = h0@M (A aliases xw), dot per edge ----
    make_M<<<(HDIM * HDIM + 255) / 256, 256, 0, stream>>>(Rg, Dl, rt_k, M);
    float* A = xw;
    h0M_kernel<<<N_NODES / 16, 256, 0, stream>>>(h0, M, A);
    decode<<<E_DEC * HDIM / 256, 256, 0, stream>>>(A, h1, edges, out);
}

// Round 11
// 923.961 us; speedup vs baseline: 3.5731x; 3.5731x over previous
//
#include <hip/hip_runtime.h>

#define N_NODES 50000
#define E_ADJ   800000
#define E_DEC   200000
#define FDIM    128
#define HDIM    64
#define NP1     (N_NODES + 1)
#define NBUK    196            // ceil(50000/256) buckets of 256 rows
#define BCAP    5120           // bucket capacity; mean 4082, sigma~64 -> 16-sigma margin
#define TILE_E  4096           // edges per part-block
#define EPB     16             // edges per thread (TILE_E/256)
#define NPBLK   196            // ceil(E_ADJ/TILE_E)

__device__ __forceinline__ int   ntl_i(const int* p)   { return __builtin_nontemporal_load(p); }
__device__ __forceinline__ float ntl_f(const float* p) { return __builtin_nontemporal_load(p); }

// ---------------------------------------------------------------------------
// CSR build, two-level bucket sort.
// P1 v2: block-local LDS histogram first -> only 196 global atomics per block
// (R10 lesson: 3.2M global atomicAdds on 784 counters = ~4082-way same-address
// contention = 1.28ms of pure serialization. LDS batching cuts global atomics
// 20x and per-counter contention to block granularity.)
// ---------------------------------------------------------------------------
__global__ void part_kernel(const int* __restrict__ rows,
                            const int* __restrict__ cols,
                            const float* __restrict__ vals,
                            int* __restrict__ gcur,
                            unsigned long long* __restrict__ bucketed)
{
    const int k   = blockIdx.y;
    const int tid = threadIdx.x;
    const long long t0 = (long long)blockIdx.x * TILE_E;

    __shared__ int hist[NBUK];
    __shared__ int sbase[NBUK];
    for (int i = tid; i < NBUK; i += 256) hist[i] = 0;
    __syncthreads();

    int lidx[EPB];
    int brl[EPB];                       // packed (bucket<<8)|row_local
#pragma unroll
    for (int it = 0; it < EPB; ++it) {
        const long long e = t0 + it * 256 + tid;
        brl[it] = -1;
        if (e < E_ADJ) {
            const int r = ntl_i(&rows[(size_t)k * E_ADJ + e]);
            const int b = r >> 8;
            brl[it] = (b << 8) | (r & 255);
            lidx[it] = atomicAdd(&hist[b], 1);      // LDS atomic
        }
    }
    __syncthreads();

    for (int i = tid; i < NBUK; i += 256)
        sbase[i] = (hist[i] > 0) ? atomicAdd(&gcur[k * NBUK + i], hist[i]) : 0;
    __syncthreads();

#pragma unroll
    for (int it = 0; it < EPB; ++it) {
        if (brl[it] >= 0) {
            const long long e = t0 + it * 256 + tid;
            const int b  = brl[it] >> 8;
            const int rl = brl[it] & 255;
            const int c  = ntl_i(&cols[(size_t)k * E_ADJ + e]);
            const float v = ntl_f(&vals[(size_t)k * E_ADJ + e]);
            const unsigned meta = (unsigned)c | ((unsigned)rl << 16);   // col < 65536
            const unsigned long long payload =
                ((unsigned long long)__float_as_uint(v) << 32) | meta;
            bucketed[((size_t)(k * NBUK + b)) * BCAP + sbase[b] + lidx[it]] = payload;
        }
    }
}

// P2: per-relation exclusive scan of bucket counts -> srt base per bucket.
__global__ void bucket_scan(const int* __restrict__ gcur, int* __restrict__ srtbase)
{
    const int k = threadIdx.x;
    if (k < 4) {
        int run = 0;
        for (int b = 0; b < NBUK; ++b) {
            srtbase[k * NBUK + b] = run;
            run += gcur[k * NBUK + b];
        }
    }
}

// P3: per-bucket row sort. LDS row-hist + scan -> row_ptr; scatter to final
// srt positions (random 8B but within a ~40KB window -> L2-absorbed).
__global__ void bucket_sort(const unsigned long long* __restrict__ bucketed,
                            const int* __restrict__ gcur,
                            const int* __restrict__ srtbase,
                            float2* __restrict__ srt,
                            int* __restrict__ row_ptr)
{
    const int b = blockIdx.x, k = blockIdx.y, tid = threadIdx.x;
    const int cnt  = gcur[k * NBUK + b];
    const int base = srtbase[k * NBUK + b];
    const unsigned long long* bk = bucketed + (size_t)(k * NBUK + b) * BCAP;

    __shared__ int s[256];
    __shared__ int cur[256];
    __shared__ int rcnt[256];
    rcnt[tid] = 0;
    __syncthreads();

    for (int i = tid; i < cnt; i += 256) {
        const unsigned meta = (unsigned)bk[i];
        atomicAdd(&rcnt[(meta >> 16) & 255], 1);
    }
    __syncthreads();

    const int v = rcnt[tid];
    s[tid] = v;
    __syncthreads();
    for (int off = 1; off < 256; off <<= 1) {
        const int t = (tid >= off) ? s[tid - off] : 0;
        __syncthreads();
        s[tid] += t;
        __syncthreads();
    }
    const int excl = s[tid] - v;

    const int n = b * 256 + tid;
    if (n < N_NODES) row_ptr[k * NP1 + n] = base + excl;
    if (b == NBUK - 1 && tid == 0) row_ptr[k * NP1 + N_NODES] = E_ADJ;
    cur[tid] = base + excl;
    __syncthreads();

    for (int i = tid; i < cnt; i += 256) {
        const unsigned long long p = bk[i];
        const unsigned meta = (unsigned)p;
        const int rl = (meta >> 16) & 255;
        const int c  = meta & 0xFFFF;
        const float val = __uint_as_float((unsigned)(p >> 32));
        const int pos = atomicAdd(&cur[rl], 1);
        srt[(size_t)k * E_ADJ + pos] = make_float2(__int_as_float(c), val);
    }
}

// ---------------------------------------------------------------------------
// Stage-1 dense transform: xw[k][n][h] = sum_f xin_k[n][f] * W[k][f][h]
// ---------------------------------------------------------------------------
template <int FIN>
__global__ void gemm_stage(const float* __restrict__ x0,
                           const float* __restrict__ x1,
                           const float* __restrict__ W,   // [4][FIN][HDIM]
                           float* __restrict__ xw)        // [4][N][HDIM]
{
    const int wave = threadIdx.x >> 6;   // relation k
    const int lane = threadIdx.x & 63;   // h
    const int n0 = blockIdx.x * 8;       // 6250 blocks * 8 = 50000 exactly

    __shared__ float sx[2][8][FIN];
    for (int i = threadIdx.x; i < 8 * FIN; i += 256) {
        const int r = i / FIN, f = i % FIN;
        sx[0][r][f] = x0[(size_t)(n0 + r) * FIN + f];
        sx[1][r][f] = x1[(size_t)(n0 + r) * FIN + f];
    }
    __syncthreads();

    const float* Wk = W + (size_t)wave * FIN * HDIM;
    const float (*xr)[FIN] = sx[wave & 1];

    float acc[8] = {0.f, 0.f, 0.f, 0.f, 0.f, 0.f, 0.f, 0.f};
#pragma unroll 4
    for (int f = 0; f < FIN; ++f) {
        const float w = Wk[(size_t)f * HDIM + lane];
#pragma unroll
        for (int r = 0; r < 8; ++r)
            acc[r] = fmaf(xr[r][f], w, acc[r]);
    }

    float* outp = xw + ((size_t)wave * N_NODES + n0) * HDIM + lane;
#pragma unroll
    for (int r = 0; r < 8; ++r)
        outp[(size_t)r * HDIM] = acc[r];
}

// ---------------------------------------------------------------------------
// Stage-1 SPMM (post-transform gather) + relu + pairwise sum.
// ---------------------------------------------------------------------------
__global__ void spmm_csr(const float2* __restrict__ srt,    // [4][E] {col,val}
                         const int*    __restrict__ row_ptr,// [4][N+1]
                         const float*  __restrict__ xw,     // [4][N][H]
                         float* __restrict__ h0, float* __restrict__ h1)
{
    const int k = threadIdx.x >> 6;
    const int lane = threadIdx.x & 63;
    const int n = blockIdx.x;

    const int s  = row_ptr[k * NP1 + n];
    const int en = row_ptr[k * NP1 + n + 1];
    const float2* sp = srt + (size_t)k * E_ADJ;
    const float*  xk = xw + (size_t)k * N_NODES * HDIM;

    float a[8] = {0.f, 0.f, 0.f, 0.f, 0.f, 0.f, 0.f, 0.f};

    for (int base = s; base < en; base += 64) {
        const int cnt = min(64, en - base);
        float2 meta = make_float2(0.f, 0.f);
        if (lane < cnt) meta = sp[base + lane];   // one coalesced meta load

        int j = 0;
        for (; j + 8 <= cnt; j += 8) {
            int   c[8];
            float v[8], g[8];
#pragma unroll
            for (int u = 0; u < 8; ++u) {
                c[u] = __shfl(__float_as_int(meta.x), j + u, 64);
                v[u] = __shfl(meta.y, j + u, 64);
            }
#pragma unroll
            for (int u = 0; u < 8; ++u)           // 8 independent gathers in flight
                g[u] = xk[(size_t)c[u] * HDIM + lane];
#pragma unroll
            for (int u = 0; u < 8; ++u)
                a[u] = fmaf(g[u], v[u], a[u]);
        }
        for (; j < cnt; ++j) {
            const int   cc = __shfl(__float_as_int(meta.x), j, 64);
            const float vv = __shfl(meta.y, j, 64);
            a[0] = fmaf(xk[(size_t)cc * HDIM + lane], vv, a[0]);
        }
    }

    float acc = ((a[0] + a[1]) + (a[2] + a[3])) + ((a[4] + a[5]) + (a[6] + a[7]));
    acc = fmaxf(acc, 0.f);

    __shared__ float sacc[4][HDIM];
    sacc[k][lane] = acc;
    __syncthreads();
    if (k == 0)      h0[(size_t)n * HDIM + lane] = sacc[0][lane] + sacc[1][lane];
    else if (k == 1) h1[(size_t)n * HDIM + lane] = sacc[2][lane] + sacc[3][lane];
}

// ---------------------------------------------------------------------------
// Stages 2-4: aggregate-then-transform (spmm(x@W) == spmm(x)@W).
// ---------------------------------------------------------------------------
__global__ void agg_csr(const float2* __restrict__ srt,
                        const int*    __restrict__ row_ptr,
                        const float*  __restrict__ x0,
                        const float*  __restrict__ x1,
                        float* __restrict__ agg)    // [4][N][H]
{
    const int k = threadIdx.x >> 6;
    const int lane = threadIdx.x & 63;
    const int n = blockIdx.x;

    const int s  = row_ptr[k * NP1 + n];
    const int en = row_ptr[k * NP1 + n + 1];
    const float2* sp = srt + (size_t)k * E_ADJ;
    const float*  xk = (k & 1) ? x1 : x0;

    float a[8] = {0.f, 0.f, 0.f, 0.f, 0.f, 0.f, 0.f, 0.f};

    for (int base = s; base < en; base += 64) {
        const int cnt = min(64, en - base);
        float2 meta = make_float2(0.f, 0.f);
        if (lane < cnt) meta = sp[base + lane];

        int j = 0;
        for (; j + 8 <= cnt; j += 8) {
            int   c[8];
            float v[8], g[8];
#pragma unroll
            for (int u = 0; u < 8; ++u) {
                c[u] = __shfl(__float_as_int(meta.x), j + u, 64);
                v[u] = __shfl(meta.y, j + u, 64);
            }
#pragma unroll
            for (int u = 0; u < 8; ++u)
                g[u] = xk[(size_t)c[u] * HDIM + lane];
#pragma unroll
            for (int u = 0; u < 8; ++u)
                a[u] = fmaf(g[u], v[u], a[u]);
        }
        for (; j < cnt; ++j) {
            const int   cc = __shfl(__float_as_int(meta.x), j, 64);
            const float vv = __shfl(meta.y, j, 64);
            a[0] = fmaf(xk[(size_t)cc * HDIM + lane], vv, a[0]);
        }
    }

    const float acc = ((a[0] + a[1]) + (a[2] + a[3])) + ((a[4] + a[5]) + (a[6] + a[7]));
    agg[((size_t)k * N_NODES + n) * HDIM + lane] = acc;
}

// y_k = relu(agg_k @ W_k); h0 = y0+y1, h1 = y2+y3.  8 nodes/block, wave = k.
__global__ void gemm2(const float* __restrict__ agg,  // [4][N][H]
                      const float* __restrict__ W,    // [4][H][H]
                      float* __restrict__ h0, float* __restrict__ h1)
{
    const int wave = threadIdx.x >> 6;   // relation k
    const int lane = threadIdx.x & 63;   // h
    const int n0 = blockIdx.x * 8;       // 6250 blocks

    __shared__ float sg[4][8][HDIM];
    for (int i = threadIdx.x; i < 4 * 8 * HDIM; i += 256) {
        const int k = i >> 9, rem = i & 511;
        const int r = rem >> 6, f = rem & 63;
        sg[k][r][f] = agg[((size_t)k * N_NODES + n0 + r) * HDIM + f];
    }
    __syncthreads();

    const float* Wk = W + (size_t)wave * HDIM * HDIM;
    float acc[8] = {0.f, 0.f, 0.f, 0.f, 0.f, 0.f, 0.f, 0.f};
#pragma unroll 4
    for (int f = 0; f < HDIM; ++f) {
        const float w = Wk[f * HDIM + lane];
#pragma unroll
        for (int r = 0; r < 8; ++r)
            acc[r] = fmaf(sg[wave][r][f], w, acc[r]);
    }
    __syncthreads();
#pragma unroll
    for (int r = 0; r < 8; ++r)
        sg[wave][r][lane] = fmaxf(acc[r], 0.f);   // reuse LDS for relu'd y
    __syncthreads();

    if (wave == 0) {
#pragma unroll
        for (int r = 0; r < 8; ++r)
            h0[(size_t)(n0 + r) * HDIM + lane] = sg[0][r][lane] + sg[1][r][lane];
    } else if (wave == 1) {
#pragma unroll
        for (int r = 0; r < 8; ++r)
            h1[(size_t)(n0 + r) * HDIM + lane] = sg[2][r][lane] + sg[3][r][lane];
    }
}

// ---------------------------------------------------------------------------
__global__ void make_M(const float* __restrict__ R, const float* __restrict__ Dl,
                       const int* __restrict__ rt_k, float* __restrict__ M)
{
    const int i = blockIdx.x * blockDim.x + threadIdx.x;
    if (i >= HDIM * HDIM) return;
    const float* d = Dl + rt_k[0] * HDIM;
    M[i] = d[i >> 6] * R[i] * d[i & 63];
}

// A[n][g] = sum_h h0[n][h] * M[h][g]   (16 rows/block, 4 waves x 4 rows)
__global__ void h0M_kernel(const float* __restrict__ h0, const float* __restrict__ M,
                           float* __restrict__ A)
{
    const int wave = threadIdx.x >> 6, lane = threadIdx.x & 63;
    const int n0 = blockIdx.x * 16;      // 3125 blocks * 16 = 50000 exactly

    __shared__ float sx[16][HDIM];
    for (int i = threadIdx.x; i < 16 * HDIM; i += 256)
        sx[i >> 6][i & 63] = h0[(size_t)n0 * HDIM + i];
    __syncthreads();

    float acc[4] = {0.f, 0.f, 0.f, 0.f};
#pragma unroll 4
    for (int f = 0; f < HDIM; ++f) {
        const float w = M[f * HDIM + lane];
#pragma unroll
        for (int r = 0; r < 4; ++r)
            acc[r] = fmaf(sx[wave * 4 + r][f], w, acc[r]);
    }
#pragma unroll
    for (int r = 0; r < 4; ++r)
        A[(size_t)(n0 + wave * 4 + r) * HDIM + lane] = acc[r];
}

// preds[e] = dot(A[i], h1[j]) — one wave per edge, 64-wide dot + reduce.
__global__ void decode(const float* __restrict__ A, const float* __restrict__ h1,
                       const int* __restrict__ edges, float* __restrict__ out)
{
    const long long t = (long long)blockIdx.x * 256 + threadIdx.x;
    const int e = (int)(t >> 6);
    const int lane = (int)(t & 63);

    const int i = edges[2 * (size_t)e];
    const int j = edges[2 * (size_t)e + 1];

    float p = A[(size_t)i * HDIM + lane] * h1[(size_t)j * HDIM + lane];
#pragma unroll
    for (int off = 32; off; off >>= 1)
        p += __shfl_down(p, off, 64);
    if (lane == 0) out[e] = p;
}

// ---------------------------------------------------------------------------
static void build_csr(const int* rows, const int* cols, const float* vals,
                      int* gcur, int* srtbase, unsigned long long* bucketed,
                      float2* srt, int* row_ptr, hipStream_t stream)
{
    hipMemsetAsync(gcur, 0, 4 * NBUK * sizeof(int), stream);
    part_kernel<<<dim3(NPBLK, 4), 256, 0, stream>>>(rows, cols, vals, gcur, bucketed);
    bucket_scan<<<1, 64, 0, stream>>>(gcur, srtbase);
    bucket_sort<<<dim3(NBUK, 4), 256, 0, stream>>>(bucketed, gcur, srtbase, srt, row_ptr);
}

extern "C" void kernel_launch(void* const* d_in, const int* in_sizes, int n_in,
                              void* d_out, int out_size, void* d_ws, size_t ws_size,
                              hipStream_t stream) {
    const int*   adj_rows = (const int*)  d_in[0];
    const int*   adj_cols = (const int*)  d_in[1];
    const float* adj_vals = (const float*)d_in[2];
    const float* feat0    = (const float*)d_in[3];
    const float* feat1    = (const float*)d_in[4];
    const float* W1       = (const float*)d_in[5];
    const float* W2       = (const float*)d_in[6];
    const float* W3       = (const float*)d_in[7];
    const float* W4       = (const float*)d_in[8];
    const float* Rg       = (const float*)d_in[9];
    const float* Dl       = (const float*)d_in[10];
    const int*   edges    = (const int*)  d_in[11];
    const int*   rt_k     = (const int*)  d_in[12];
    float* out = (float*)d_out;

    const size_t NH = (size_t)N_NODES * HDIM;
    float* ws = (float*)d_ws;
    float*  xw      = ws;                         // 4*NH (also: bucketed alias, agg, A)
    float*  h0      = xw + 4 * NH;                // NH
    float*  h1      = h0 + NH;                    // NH
    float2* srt     = (float2*)(h1 + NH);         // 4*E float2 = 6.4M f
    int*    row_ptr = (int*)(h1 + NH + 8 * (size_t)E_ADJ); // 4*(N+1)
    int*    gcur    = row_ptr + 4 * NP1 + 60;     // 4*NBUK
    int*    srtbase = gcur + 4 * NBUK;            // 4*NBUK
    float*  M       = (float*)(srtbase + 4 * NBUK + 32); // 4096 f
    // bucketed aliases xw region: 4*196*5120*8B = 32.1MB < 51.2MB; it is dead
    // before anything writes xw (P3 of each build consumes it first).
    unsigned long long* bucketed = (unsigned long long*)xw;
    // total ~= 25.9M floats ~= 103 MB

    const int* r2 = adj_rows + 4 * (size_t)E_ADJ;
    const int* c2 = adj_cols + 4 * (size_t)E_ADJ;
    const float* v2 = adj_vals + 4 * (size_t)E_ADJ;

    // ---- CSR for adjacency group A (stages 1 & 2) ----
    build_csr(adj_rows, adj_cols, adj_vals, gcur, srtbase, bucketed, srt, row_ptr, stream);

    // ---- stage 1: transform-then-aggregate (F=128 -> gather 64-dim xw) ----
    gemm_stage<FDIM><<<N_NODES / 8, 256, 0, stream>>>(feat0, feat1, W1, xw);
    spmm_csr<<<N_NODES, 256, 0, stream>>>(srt, row_ptr, xw, h0, h1);

    // ---- stage 2: aggregate-then-transform ----
    agg_csr<<<N_NODES, 256, 0, stream>>>(srt, row_ptr, h0, h1, xw);
    gemm2<<<N_NODES / 8, 256, 0, stream>>>(xw, W2, h0, h1);

    // ---- CSR for adjacency group B (stages 3 & 4) ----
    build_csr(r2, c2, v2, gcur, srtbase, bucketed, srt, row_ptr, stream);

    // ---- stage 3 ----
    agg_csr<<<N_NODES, 256, 0, stream>>>(srt, row_ptr, h0, h1, xw);
    gemm2<<<N_NODES / 8, 256, 0, stream>>>(xw, W3, h0, h1);

    // ---- stage 4 ----
    agg_csr<<<N_NODES, 256, 0, stream>>>(srt, row_ptr, h0, h1, xw);
    gemm2<<<N_NODES / 8, 256, 0, stream>>>(xw, W4, h0, h1);

    // ---- decode: M, A = h0@M (A aliases xw), dot per edge ----
    make_M<<<(HDIM * HDIM + 255) / 256, 256, 0, stream>>>(Rg, Dl, rt_k, M);
    float* A = xw;
    h0M_kernel<<<N_NODES / 16, 256, 0, stream>>>(h0, M, A);
    decode<<<E_DEC * HDIM / 256, 256, 0, stream>>>(A, h1, edges, out);
}

// Round 12
// 845.271 us; speedup vs baseline: 3.9057x; 1.0931x over previous
//
#include <hip/hip_runtime.h>

#define N_NODES 50000
#define E_ADJ   800000
#define E_DEC   200000
#define FDIM    128
#define HDIM    64
#define NP1     (N_NODES + 1)
#define NBUK    196            // ceil(50000/256) buckets of 256 rows
#define BCAP    5120           // bucket capacity; mean 4082 -> 16-sigma margin
#define TILE_E  4096           // edges per part-block
#define EPB     16             // edges per thread
#define NPBLK   196            // ceil(E_ADJ/TILE_E)

typedef _Float16 f16;

__device__ __forceinline__ int   ntl_i(const int* p)   { return __builtin_nontemporal_load(p); }
__device__ __forceinline__ float ntl_f(const float* p) { return __builtin_nontemporal_load(p); }

// ---------------------------------------------------------------------------
// CSR build, two-level bucket sort (R11 structure, unchanged).
// ---------------------------------------------------------------------------
__global__ void part_kernel(const int* __restrict__ rows,
                            const int* __restrict__ cols,
                            const float* __restrict__ vals,
                            int* __restrict__ gcur,
                            unsigned long long* __restrict__ bucketed)
{
    const int k   = blockIdx.y;
    const int tid = threadIdx.x;
    const long long t0 = (long long)blockIdx.x * TILE_E;

    __shared__ int hist[NBUK];
    __shared__ int sbase[NBUK];
    for (int i = tid; i < NBUK; i += 256) hist[i] = 0;
    __syncthreads();

    int lidx[EPB];
    int brl[EPB];                       // packed (bucket<<8)|row_local
#pragma unroll
    for (int it = 0; it < EPB; ++it) {
        const long long e = t0 + it * 256 + tid;
        brl[it] = -1;
        if (e < E_ADJ) {
            const int r = ntl_i(&rows[(size_t)k * E_ADJ + e]);
            const int b = r >> 8;
            brl[it] = (b << 8) | (r & 255);
            lidx[it] = atomicAdd(&hist[b], 1);      // LDS atomic
        }
    }
    __syncthreads();

    for (int i = tid; i < NBUK; i += 256)
        sbase[i] = (hist[i] > 0) ? atomicAdd(&gcur[k * NBUK + i], hist[i]) : 0;
    __syncthreads();

#pragma unroll
    for (int it = 0; it < EPB; ++it) {
        if (brl[it] >= 0) {
            const long long e = t0 + it * 256 + tid;
            const int b  = brl[it] >> 8;
            const int rl = brl[it] & 255;
            const int c  = ntl_i(&cols[(size_t)k * E_ADJ + e]);
            const float v = ntl_f(&vals[(size_t)k * E_ADJ + e]);
            const unsigned meta = (unsigned)c | ((unsigned)rl << 16);   // col < 65536
            const unsigned long long payload =
                ((unsigned long long)__float_as_uint(v) << 32) | meta;
            bucketed[((size_t)(k * NBUK + b)) * BCAP + sbase[b] + lidx[it]] = payload;
        }
    }
}

__global__ void bucket_scan(const int* __restrict__ gcur, int* __restrict__ srtbase)
{
    const int k = threadIdx.x;
    if (k < 4) {
        int run = 0;
        for (int b = 0; b < NBUK; ++b) {
            srtbase[k * NBUK + b] = run;
            run += gcur[k * NBUK + b];
        }
    }
}

__global__ void bucket_sort(const unsigned long long* __restrict__ bucketed,
                            const int* __restrict__ gcur,
                            const int* __restrict__ srtbase,
                            float2* __restrict__ srt,
                            int* __restrict__ row_ptr)
{
    const int b = blockIdx.x, k = blockIdx.y, tid = threadIdx.x;
    const int cnt  = gcur[k * NBUK + b];
    const int base = srtbase[k * NBUK + b];
    const unsigned long long* bk = bucketed + (size_t)(k * NBUK + b) * BCAP;

    __shared__ int s[256];
    __shared__ int cur[256];
    __shared__ int rcnt[256];
    rcnt[tid] = 0;
    __syncthreads();

    for (int i = tid; i < cnt; i += 256) {
        const unsigned meta = (unsigned)bk[i];
        atomicAdd(&rcnt[(meta >> 16) & 255], 1);
    }
    __syncthreads();

    const int v = rcnt[tid];
    s[tid] = v;
    __syncthreads();
    for (int off = 1; off < 256; off <<= 1) {
        const int t = (tid >= off) ? s[tid - off] : 0;
        __syncthreads();
        s[tid] += t;
        __syncthreads();
    }
    const int excl = s[tid] - v;

    const int n = b * 256 + tid;
    if (n < N_NODES) row_ptr[k * NP1 + n] = base + excl;
    if (b == NBUK - 1 && tid == 0) row_ptr[k * NP1 + N_NODES] = E_ADJ;
    cur[tid] = base + excl;
    __syncthreads();

    for (int i = tid; i < cnt; i += 256) {
        const unsigned long long p = bk[i];
        const unsigned meta = (unsigned)p;
        const int rl = (meta >> 16) & 255;
        const int c  = meta & 0xFFFF;
        const float val = __uint_as_float((unsigned)(p >> 32));
        const int pos = atomicAdd(&cur[rl], 1);
        srt[(size_t)k * E_ADJ + pos] = make_float2(__int_as_float(c), val);
    }
}

// ---------------------------------------------------------------------------
// Stage-1 dense transform: xw (fp16 out) = xin @ W
// ---------------------------------------------------------------------------
template <int FIN>
__global__ void gemm_stage(const float* __restrict__ x0,
                           const float* __restrict__ x1,
                           const float* __restrict__ W,   // [4][FIN][HDIM]
                           f16* __restrict__ xw)          // [4][N][HDIM] fp16
{
    const int wave = threadIdx.x >> 6;   // relation k
    const int lane = threadIdx.x & 63;   // h
    const int n0 = blockIdx.x * 8;       // 6250 blocks

    __shared__ float sx[2][8][FIN];
    for (int i = threadIdx.x; i < 8 * FIN; i += 256) {
        const int r = i / FIN, f = i % FIN;
        sx[0][r][f] = x0[(size_t)(n0 + r) * FIN + f];
        sx[1][r][f] = x1[(size_t)(n0 + r) * FIN + f];
    }
    __syncthreads();

    const float* Wk = W + (size_t)wave * FIN * HDIM;
    const float (*xr)[FIN] = sx[wave & 1];

    float acc[8] = {0.f, 0.f, 0.f, 0.f, 0.f, 0.f, 0.f, 0.f};
#pragma unroll 4
    for (int f = 0; f < FIN; ++f) {
        const float w = Wk[(size_t)f * HDIM + lane];
#pragma unroll
        for (int r = 0; r < 8; ++r)
            acc[r] = fmaf(xr[r][f], w, acc[r]);
    }

    f16* outp = xw + ((size_t)wave * N_NODES + n0) * HDIM + lane;
#pragma unroll
    for (int r = 0; r < 8; ++r)
        outp[(size_t)r * HDIM] = (f16)acc[r];
}

// ---------------------------------------------------------------------------
// Stage-1 SPMM: gather fp16 xw rows (128B/edge), accumulate fp32.
// ---------------------------------------------------------------------------
__global__ void spmm_csr(const float2* __restrict__ srt,    // [4][E] {col,val}
                         const int*    __restrict__ row_ptr,// [4][N+1]
                         const f16*    __restrict__ xw,     // [4][N][H] fp16
                         f16* __restrict__ h0, f16* __restrict__ h1)
{
    const int k = threadIdx.x >> 6;
    const int lane = threadIdx.x & 63;
    const int n = blockIdx.x;

    const int s  = row_ptr[k * NP1 + n];
    const int en = row_ptr[k * NP1 + n + 1];
    const float2* sp = srt + (size_t)k * E_ADJ;
    const f16*    xk = xw + (size_t)k * N_NODES * HDIM;

    float a[8] = {0.f, 0.f, 0.f, 0.f, 0.f, 0.f, 0.f, 0.f};

    for (int base = s; base < en; base += 64) {
        const int cnt = min(64, en - base);
        float2 meta = make_float2(0.f, 0.f);
        if (lane < cnt) meta = sp[base + lane];

        int j = 0;
        for (; j + 8 <= cnt; j += 8) {
            int   c[8];
            float v[8], g[8];
#pragma unroll
            for (int u = 0; u < 8; ++u) {
                c[u] = __shfl(__float_as_int(meta.x), j + u, 64);
                v[u] = __shfl(meta.y, j + u, 64);
            }
#pragma unroll
            for (int u = 0; u < 8; ++u)           // 8 independent fp16 gathers
                g[u] = (float)xk[(size_t)c[u] * HDIM + lane];
#pragma unroll
            for (int u = 0; u < 8; ++u)
                a[u] = fmaf(g[u], v[u], a[u]);
        }
        for (; j < cnt; ++j) {
            const int   cc = __shfl(__float_as_int(meta.x), j, 64);
            const float vv = __shfl(meta.y, j, 64);
            a[0] = fmaf((float)xk[(size_t)cc * HDIM + lane], vv, a[0]);
        }
    }

    float acc = ((a[0] + a[1]) + (a[2] + a[3])) + ((a[4] + a[5]) + (a[6] + a[7]));
    acc = fmaxf(acc, 0.f);

    __shared__ float sacc[4][HDIM];
    sacc[k][lane] = acc;
    __syncthreads();
    if (k == 0)      h0[(size_t)n * HDIM + lane] = (f16)(sacc[0][lane] + sacc[1][lane]);
    else if (k == 1) h1[(size_t)n * HDIM + lane] = (f16)(sacc[2][lane] + sacc[3][lane]);
}

// ---------------------------------------------------------------------------
// Stages 2-4: aggregate (fp16 gathers) then transform.
// ---------------------------------------------------------------------------
__global__ void agg_csr(const float2* __restrict__ srt,
                        const int*    __restrict__ row_ptr,
                        const f16*    __restrict__ x0,
                        const f16*    __restrict__ x1,
                        f16* __restrict__ agg)    // [4][N][H] fp16
{
    const int k = threadIdx.x >> 6;
    const int lane = threadIdx.x & 63;
    const int n = blockIdx.x;

    const int s  = row_ptr[k * NP1 + n];
    const int en = row_ptr[k * NP1 + n + 1];
    const float2* sp = srt + (size_t)k * E_ADJ;
    const f16*    xk = (k & 1) ? x1 : x0;

    float a[8] = {0.f, 0.f, 0.f, 0.f, 0.f, 0.f, 0.f, 0.f};

    for (int base = s; base < en; base += 64) {
        const int cnt = min(64, en - base);
        float2 meta = make_float2(0.f, 0.f);
        if (lane < cnt) meta = sp[base + lane];

        int j = 0;
        for (; j + 8 <= cnt; j += 8) {
            int   c[8];
            float v[8], g[8];
#pragma unroll
            for (int u = 0; u < 8; ++u) {
                c[u] = __shfl(__float_as_int(meta.x), j + u, 64);
                v[u] = __shfl(meta.y, j + u, 64);
            }
#pragma unroll
            for (int u = 0; u < 8; ++u)
                g[u] = (float)xk[(size_t)c[u] * HDIM + lane];
#pragma unroll
            for (int u = 0; u < 8; ++u)
                a[u] = fmaf(g[u], v[u], a[u]);
        }
        for (; j < cnt; ++j) {
            const int   cc = __shfl(__float_as_int(meta.x), j, 64);
            const float vv = __shfl(meta.y, j, 64);
            a[0] = fmaf((float)xk[(size_t)cc * HDIM + lane], vv, a[0]);
        }
    }

    const float acc = ((a[0] + a[1]) + (a[2] + a[3])) + ((a[4] + a[5]) + (a[6] + a[7]));
    agg[((size_t)k * N_NODES + n) * HDIM + lane] = (f16)acc;
}

// y_k = relu(agg_k @ W_k); h0 = y0+y1, h1 = y2+y3.
__global__ void gemm2(const f16* __restrict__ agg,   // [4][N][H] fp16
                      const float* __restrict__ W,   // [4][H][H]
                      f16* __restrict__ h0, f16* __restrict__ h1)
{
    const int wave = threadIdx.x >> 6;   // relation k
    const int lane = threadIdx.x & 63;   // h
    const int n0 = blockIdx.x * 8;       // 6250 blocks

    __shared__ float sg[4][8][HDIM];
    for (int i = threadIdx.x; i < 4 * 8 * HDIM; i += 256) {
        const int k = i >> 9, rem = i & 511;
        const int r = rem >> 6, f = rem & 63;
        sg[k][r][f] = (float)agg[((size_t)k * N_NODES + n0 + r) * HDIM + f];
    }
    __syncthreads();

    const float* Wk = W + (size_t)wave * HDIM * HDIM;
    float acc[8] = {0.f, 0.f, 0.f, 0.f, 0.f, 0.f, 0.f, 0.f};
#pragma unroll 4
    for (int f = 0; f < HDIM; ++f) {
        const float w = Wk[f * HDIM + lane];
#pragma unroll
        for (int r = 0; r < 8; ++r)
            acc[r] = fmaf(sg[wave][r][f], w, acc[r]);
    }
    __syncthreads();
#pragma unroll
    for (int r = 0; r < 8; ++r)
        sg[wave][r][lane] = fmaxf(acc[r], 0.f);
    __syncthreads();

    if (wave == 0) {
#pragma unroll
        for (int r = 0; r < 8; ++r)
            h0[(size_t)(n0 + r) * HDIM + lane] = (f16)(sg[0][r][lane] + sg[1][r][lane]);
    } else if (wave == 1) {
#pragma unroll
        for (int r = 0; r < 8; ++r)
            h1[(size_t)(n0 + r) * HDIM + lane] = (f16)(sg[2][r][lane] + sg[3][r][lane]);
    }
}

// ---------------------------------------------------------------------------
__global__ void make_M(const float* __restrict__ R, const float* __restrict__ Dl,
                       const int* __restrict__ rt_k, float* __restrict__ M)
{
    const int i = blockIdx.x * blockDim.x + threadIdx.x;
    if (i >= HDIM * HDIM) return;
    const float* d = Dl + rt_k[0] * HDIM;
    M[i] = d[i >> 6] * R[i] * d[i & 63];
}

// A[n][g] = sum_h h0[n][h] * M[h][g]   (fp16 out)
__global__ void h0M_kernel(const f16* __restrict__ h0, const float* __restrict__ M,
                           f16* __restrict__ A)
{
    const int wave = threadIdx.x >> 6, lane = threadIdx.x & 63;
    const int n0 = blockIdx.x * 16;      // 3125 blocks

    __shared__ float sx[16][HDIM];
    for (int i = threadIdx.x; i < 16 * HDIM; i += 256)
        sx[i >> 6][i & 63] = (float)h0[(size_t)n0 * HDIM + i];
    __syncthreads();

    float acc[4] = {0.f, 0.f, 0.f, 0.f};
#pragma unroll 4
    for (int f = 0; f < HDIM; ++f) {
        const float w = M[f * HDIM + lane];
#pragma unroll
        for (int r = 0; r < 4; ++r)
            acc[r] = fmaf(sx[wave * 4 + r][f], w, acc[r]);
    }
#pragma unroll
    for (int r = 0; r < 4; ++r)
        A[(size_t)(n0 + wave * 4 + r) * HDIM + lane] = (f16)acc[r];
}

// preds[e] = dot(A[i], h1[j])
__global__ void decode(const f16* __restrict__ A, const f16* __restrict__ h1,
                       const int* __restrict__ edges, float* __restrict__ out)
{
    const long long t = (long long)blockIdx.x * 256 + threadIdx.x;
    const int e = (int)(t >> 6);
    const int lane = (int)(t & 63);

    const int i = edges[2 * (size_t)e];
    const int j = edges[2 * (size_t)e + 1];

    float p = (float)A[(size_t)i * HDIM + lane] * (float)h1[(size_t)j * HDIM + lane];
#pragma unroll
    for (int off = 32; off; off >>= 1)
        p += __shfl_down(p, off, 64);
    if (lane == 0) out[e] = p;
}

// ---------------------------------------------------------------------------
static void build_csr(const int* rows, const int* cols, const float* vals,
                      int* gcur, int* srtbase, unsigned long long* bucketed,
                      float2* srt, int* row_ptr, hipStream_t stream)
{
    hipMemsetAsync(gcur, 0, 4 * NBUK * sizeof(int), stream);
    part_kernel<<<dim3(NPBLK, 4), 256, 0, stream>>>(rows, cols, vals, gcur, bucketed);
    bucket_scan<<<1, 64, 0, stream>>>(gcur, srtbase);
    bucket_sort<<<dim3(NBUK, 4), 256, 0, stream>>>(bucketed, gcur, srtbase, srt, row_ptr);
}

extern "C" void kernel_launch(void* const* d_in, const int* in_sizes, int n_in,
                              void* d_out, int out_size, void* d_ws, size_t ws_size,
                              hipStream_t stream) {
    const int*   adj_rows = (const int*)  d_in[0];
    const int*   adj_cols = (const int*)  d_in[1];
    const float* adj_vals = (const float*)d_in[2];
    const float* feat0    = (const float*)d_in[3];
    const float* feat1    = (const float*)d_in[4];
    const float* W1       = (const float*)d_in[5];
    const float* W2       = (const float*)d_in[6];
    const float* W3       = (const float*)d_in[7];
    const float* W4       = (const float*)d_in[8];
    const float* Rg       = (const float*)d_in[9];
    const float* Dl       = (const float*)d_in[10];
    const int*   edges    = (const int*)  d_in[11];
    const int*   rt_k     = (const int*)  d_in[12];
    float* out = (float*)d_out;

    const size_t NH = (size_t)N_NODES * HDIM;       // 3.2M
    float* ws = (float*)d_ws;
    // layout (float offsets):
    f16*    xwh     = (f16*)ws;                     // 4*NH halfs = 2*NH floats (also agg, A)
    f16*    h0      = (f16*)(ws + 2 * NH);          // NH halfs = NH/2 floats
    f16*    h1      = (f16*)(ws + 2 * NH + NH / 2); // NH halfs
    float2* srt     = (float2*)(ws + 3 * NH);       // 4E float2 = 6.4M floats
    int*    row_ptr = (int*)(ws + 3 * NH + 8 * (size_t)E_ADJ); // 4*(N+1)
    int*    gcur    = row_ptr + 4 * NP1 + 60;       // 4*NBUK
    int*    srtbase = gcur + 4 * NBUK;              // 4*NBUK
    float*  M       = (float*)(srtbase + 4 * NBUK + 32);       // 4096 f
    unsigned long long* bucketed =
        (unsigned long long*)(M + HDIM * HDIM + 64);           // 4*NBUK*BCAP u64 = 32.1MB
    // total ~= 3*NH + 6.4M + ~0.2M + 8.03M ~= 24.3M floats ~= 97.4 MB

    const int* r2 = adj_rows + 4 * (size_t)E_ADJ;
    const int* c2 = adj_cols + 4 * (size_t)E_ADJ;
    const float* v2 = adj_vals + 4 * (size_t)E_ADJ;

    // ---- CSR for adjacency group A (stages 1 & 2) ----
    build_csr(adj_rows, adj_cols, adj_vals, gcur, srtbase, bucketed, srt, row_ptr, stream);

    // ---- stage 1: transform-then-aggregate ----
    gemm_stage<FDIM><<<N_NODES / 8, 256, 0, stream>>>(feat0, feat1, W1, xwh);
    spmm_csr<<<N_NODES, 256, 0, stream>>>(srt, row_ptr, xwh, h0, h1);

    // ---- stage 2: aggregate-then-transform ----
    agg_csr<<<N_NODES, 256, 0, stream>>>(srt, row_ptr, h0, h1, xwh);
    gemm2<<<N_NODES / 8, 256, 0, stream>>>(xwh, W2, h0, h1);

    // ---- CSR for adjacency group B (stages 3 & 4) ----
    build_csr(r2, c2, v2, gcur, srtbase, bucketed, srt, row_ptr, stream);

    // ---- stage 3 ----
    agg_csr<<<N_NODES, 256, 0, stream>>>(srt, row_ptr, h0, h1, xwh);
    gemm2<<<N_NODES / 8, 256, 0, stream>>>(xwh, W3, h0, h1);

    // ---- stage 4 ----
    agg_csr<<<N_NODES, 256, 0, stream>>>(srt, row_ptr, h0, h1, xwh);
    gemm2<<<N_NODES / 8, 256, 0, stream>>>(xwh, W4, h0, h1);

    // ---- decode: M, A = h0@M (fp16, aliases xwh), dot per edge ----
    make_M<<<(HDIM * HDIM + 255) / 256, 256, 0, stream>>>(Rg, Dl, rt_k, M);
    f16* A = xwh;
    h0M_kernel<<<N_NODES / 16, 256, 0, stream>>>(h0, M, A);
    decode<<<E_DEC * HDIM / 256, 256, 0, stream>>>(A, h1, edges, out);
}

// Round 14
// 738.663 us; speedup vs baseline: 4.4694x; 1.1443x over previous
//
#include <hip/hip_runtime.h>

#define N_NODES 50000
#define E_ADJ   800000
#define E_DEC   200000
#define FDIM    128
#define HDIM    64
#define NP1     (N_NODES + 1)
#define NBUK    196            // ceil(50000/256) buckets of 256 rows
#define BCAP    5120           // bucket capacity; mean 4082 -> 16-sigma margin
#define TILE_E  4096           // edges per part-block
#define EPB     16             // edges per thread
#define NPBLK   196            // ceil(E_ADJ/TILE_E)

typedef _Float16 f16;
typedef __attribute__((ext_vector_type(2))) _Float16 f16x2;

__device__ __forceinline__ int   ntl_i(const int* p)   { return __builtin_nontemporal_load(p); }
__device__ __forceinline__ float ntl_f(const float* p) { return __builtin_nontemporal_load(p); }

// ---------------------------------------------------------------------------
// CSR build, two-level bucket sort (R11 structure, unchanged).
// ---------------------------------------------------------------------------
__global__ void part_kernel(const int* __restrict__ rows,
                            const int* __restrict__ cols,
                            const float* __restrict__ vals,
                            int* __restrict__ gcur,
                            unsigned long long* __restrict__ bucketed)
{
    const int k   = blockIdx.y;
    const int tid = threadIdx.x;
    const long long t0 = (long long)blockIdx.x * TILE_E;

    __shared__ int hist[NBUK];
    __shared__ int sbase[NBUK];
    for (int i = tid; i < NBUK; i += 256) hist[i] = 0;
    __syncthreads();

    int lidx[EPB];
    int brl[EPB];                       // packed (bucket<<8)|row_local
#pragma unroll
    for (int it = 0; it < EPB; ++it) {
        const long long e = t0 + it * 256 + tid;
        brl[it] = -1;
        if (e < E_ADJ) {
            const int r = ntl_i(&rows[(size_t)k * E_ADJ + e]);
            const int b = r >> 8;
            brl[it] = (b << 8) | (r & 255);
            lidx[it] = atomicAdd(&hist[b], 1);      // LDS atomic
        }
    }
    __syncthreads();

    for (int i = tid; i < NBUK; i += 256)
        sbase[i] = (hist[i] > 0) ? atomicAdd(&gcur[k * NBUK + i], hist[i]) : 0;
    __syncthreads();

#pragma unroll
    for (int it = 0; it < EPB; ++it) {
        if (brl[it] >= 0) {
            const long long e = t0 + it * 256 + tid;
            const int b  = brl[it] >> 8;
            const int rl = brl[it] & 255;
            const int c  = ntl_i(&cols[(size_t)k * E_ADJ + e]);
            const float v = ntl_f(&vals[(size_t)k * E_ADJ + e]);
            const unsigned meta = (unsigned)c | ((unsigned)rl << 16);   // col < 65536
            const unsigned long long payload =
                ((unsigned long long)__float_as_uint(v) << 32) | meta;
            bucketed[((size_t)(k * NBUK + b)) * BCAP + sbase[b] + lidx[it]] = payload;
        }
    }
}

__global__ void bucket_scan(const int* __restrict__ gcur, int* __restrict__ srtbase)
{
    const int k = threadIdx.x;
    if (k < 4) {
        int run = 0;
        for (int b = 0; b < NBUK; ++b) {
            srtbase[k * NBUK + b] = run;
            run += gcur[k * NBUK + b];
        }
    }
}

__global__ void bucket_sort(const unsigned long long* __restrict__ bucketed,
                            const int* __restrict__ gcur,
                            const int* __restrict__ srtbase,
                            float2* __restrict__ srt,
                            int* __restrict__ row_ptr)
{
    const int b = blockIdx.x, k = blockIdx.y, tid = threadIdx.x;
    const int cnt  = gcur[k * NBUK + b];
    const int base = srtbase[k * NBUK + b];
    const unsigned long long* bk = bucketed + (size_t)(k * NBUK + b) * BCAP;

    __shared__ int s[256];
    __shared__ int cur[256];
    __shared__ int rcnt[256];
    rcnt[tid] = 0;
    __syncthreads();

    for (int i = tid; i < cnt; i += 256) {
        const unsigned meta = (unsigned)bk[i];
        atomicAdd(&rcnt[(meta >> 16) & 255], 1);
    }
    __syncthreads();

    const int v = rcnt[tid];
    s[tid] = v;
    __syncthreads();
    for (int off = 1; off < 256; off <<= 1) {
        const int t = (tid >= off) ? s[tid - off] : 0;
        __syncthreads();
        s[tid] += t;
        __syncthreads();
    }
    const int excl = s[tid] - v;

    const int n = b * 256 + tid;
    if (n < N_NODES) row_ptr[k * NP1 + n] = base + excl;
    if (b == NBUK - 1 && tid == 0) row_ptr[k * NP1 + N_NODES] = E_ADJ;
    cur[tid] = base + excl;
    __syncthreads();

    for (int i = tid; i < cnt; i += 256) {
        const unsigned long long p = bk[i];
        const unsigned meta = (unsigned)p;
        const int rl = (meta >> 16) & 255;
        const int c  = meta & 0xFFFF;
        const float val = __uint_as_float((unsigned)(p >> 32));
        const int pos = atomicAdd(&cur[rl], 1);
        srt[(size_t)k * E_ADJ + pos] = make_float2(__int_as_float(c), val);
    }
}

// ---------------------------------------------------------------------------
// Paired-edge fp16x2 gather core. Lanes 0-31 process even edges, 32-63 odd;
// each lane covers h = {2*(lane&31), +1} (one 4B load spans 2 h-values).
// One load instruction now covers TWO rows' worth of edges vs one before;
// shuffles per edge drop 4x. Returns half-combined sums (valid on lanes<32).
// ---------------------------------------------------------------------------
__device__ __forceinline__ float2 gather_pairs(const float2* __restrict__ sp,
                                               int s, int en,
                                               const f16* __restrict__ xk,
                                               int lane)
{
    const int half = lane >> 5;
    const int hl   = lane & 31;
    float2 a0 = {0.f, 0.f}, a1 = {0.f, 0.f}, a2 = {0.f, 0.f}, a3 = {0.f, 0.f};

    for (int base = s; base < en; base += 64) {
        const int cnt = min(64, en - base);
        float2 meta = make_float2(0.f, 0.f);           // pad: col0/val0 is harmless
        if (lane < cnt) meta = sp[base + lane];
        const int npair = (cnt + 1) >> 1;
        int p = 0;
        for (; p + 4 <= npair; p += 4) {
            int c[4]; float v[4];
#pragma unroll
            for (int u = 0; u < 4; ++u) {
                const int sel = 2 * (p + u) + half;
                c[u] = __shfl(__float_as_int(meta.x), sel, 64);
                v[u] = __shfl(meta.y, sel, 64);
            }
            f16x2 g[4];
#pragma unroll
            for (int u = 0; u < 4; ++u)                // 4 independent 4B gathers
                g[u] = *(const f16x2*)(xk + (size_t)c[u] * HDIM + hl * 2);
            a0.x = fmaf((float)g[0].x, v[0], a0.x);
            a0.y = fmaf((float)g[0].y, v[0], a0.y);
            a1.x = fmaf((float)g[1].x, v[1], a1.x);
            a1.y = fmaf((float)g[1].y, v[1], a1.y);
            a2.x = fmaf((float)g[2].x, v[2], a2.x);
            a2.y = fmaf((float)g[2].y, v[2], a2.y);
            a3.x = fmaf((float)g[3].x, v[3], a3.x);
            a3.y = fmaf((float)g[3].y, v[3], a3.y);
        }
        for (; p < npair; ++p) {
            const int sel = 2 * p + half;
            const int cc = __shfl(__float_as_int(meta.x), sel, 64);
            const float vv = __shfl(meta.y, sel, 64);
            const f16x2 g = *(const f16x2*)(xk + (size_t)cc * HDIM + hl * 2);
            a0.x = fmaf((float)g.x, vv, a0.x);
            a0.y = fmaf((float)g.y, vv, a0.y);
        }
    }
    float2 t;
    t.x = (a0.x + a1.x) + (a2.x + a3.x);
    t.y = (a0.y + a1.y) + (a2.y + a3.y);
    t.x += __shfl(t.x, lane + 32, 64);   // combine odd/even-edge halves
    t.y += __shfl(t.y, lane + 32, 64);
    return t;                            // valid on lanes < 32
}

// ---------------------------------------------------------------------------
// Stage-1 dense transform: xw (fp16 out) = xin @ W
// ---------------------------------------------------------------------------
template <int FIN>
__global__ void gemm_stage(const float* __restrict__ x0,
                           const float* __restrict__ x1,
                           const float* __restrict__ W,   // [4][FIN][HDIM]
                           f16* __restrict__ xw)          // [4][N][HDIM] fp16
{
    const int wave = threadIdx.x >> 6;   // relation k
    const int lane = threadIdx.x & 63;   // h
    const int n0 = blockIdx.x * 8;       // 6250 blocks

    __shared__ float sx[2][8][FIN];
    for (int i = threadIdx.x; i < 8 * FIN; i += 256) {
        const int r = i / FIN, f = i % FIN;
        sx[0][r][f] = x0[(size_t)(n0 + r) * FIN + f];
        sx[1][r][f] = x1[(size_t)(n0 + r) * FIN + f];
    }
    __syncthreads();

    const float* Wk = W + (size_t)wave * FIN * HDIM;
    const float (*xr)[FIN] = sx[wave & 1];

    float acc[8] = {0.f, 0.f, 0.f, 0.f, 0.f, 0.f, 0.f, 0.f};
#pragma unroll 4
    for (int f = 0; f < FIN; ++f) {
        const float w = Wk[(size_t)f * HDIM + lane];
#pragma unroll
        for (int r = 0; r < 8; ++r)
            acc[r] = fmaf(xr[r][f], w, acc[r]);
    }

    f16* outp = xw + ((size_t)wave * N_NODES + n0) * HDIM + lane;
#pragma unroll
    for (int r = 0; r < 8; ++r)
        outp[(size_t)r * HDIM] = (f16)acc[r];
}

// ---------------------------------------------------------------------------
// Stage-1 SPMM, relation-per-block (k = blockIdx&3): with round-robin
// blockIdx->XCD, relation k runs only on XCDs {k,k+4} so each XCD's L2 holds
// one 6.4MB table slice instead of all 25.6MB (R12: FETCH showed 8x re-fetch).
// Writes per-relation relu'd y; combine kernel sums pairs afterwards.
// ---------------------------------------------------------------------------
__global__ void spmm_csr(const float2* __restrict__ srt,
                         const int*    __restrict__ row_ptr,
                         const f16*    __restrict__ xw,     // [4][N][H]
                         f16* __restrict__ y)               // [4][N][H] relu'd
{
    const int b = blockIdx.x, k = b & 3, g = b >> 2;        // 50000 blocks
    const int wave = threadIdx.x >> 6, lane = threadIdx.x & 63;
    const int n = g * 4 + wave;

    const int s  = row_ptr[k * NP1 + n];
    const int en = row_ptr[k * NP1 + n + 1];
    float2 t = gather_pairs(srt + (size_t)k * E_ADJ, s, en,
                            xw + (size_t)k * N_NODES * HDIM, lane);
    if (lane < 32) {
        f16x2 o;
        o.x = (f16)fmaxf(t.x, 0.f);
        o.y = (f16)fmaxf(t.y, 0.f);
        *(f16x2*)(y + ((size_t)k * N_NODES + n) * HDIM + lane * 2) = o;
    }
}

// h0 = y0+y1, h1 = y2+y3 (y already relu'd per relation).
__global__ void combine_kernel(const f16* __restrict__ y,
                               f16* __restrict__ h0, f16* __restrict__ h1)
{
    const size_t NHh = (size_t)N_NODES * HDIM / 2;
    const size_t i = (size_t)blockIdx.x * 256 + threadIdx.x;   // 6250 blocks exact
    const f16x2 a = ((const f16x2*)y)[i];
    const f16x2 b = ((const f16x2*)y)[NHh + i];
    const f16x2 c = ((const f16x2*)y)[2 * NHh + i];
    const f16x2 d = ((const f16x2*)y)[3 * NHh + i];
    f16x2 o0, o1;
    o0.x = (f16)((float)a.x + (float)b.x);
    o0.y = (f16)((float)a.y + (float)b.y);
    o1.x = (f16)((float)c.x + (float)d.x);
    o1.y = (f16)((float)c.y + (float)d.y);
    ((f16x2*)h0)[i] = o0;
    ((f16x2*)h1)[i] = o1;
}

// ---------------------------------------------------------------------------
// Stages 2-4: aggregate, relation-per-block (no cross-wave combine needed).
// ---------------------------------------------------------------------------
__global__ void agg_csr(const float2* __restrict__ srt,
                        const int*    __restrict__ row_ptr,
                        const f16*    __restrict__ h0,
                        const f16*    __restrict__ h1,
                        f16* __restrict__ agg)    // [4][N][H]
{
    const int b = blockIdx.x, k = b & 3, g = b >> 2;        // 50000 blocks
    const int wave = threadIdx.x >> 6, lane = threadIdx.x & 63;
    const int n = g * 4 + wave;

    const int s  = row_ptr[k * NP1 + n];
    const int en = row_ptr[k * NP1 + n + 1];
    const f16* xk = (k & 1) ? h1 : h0;
    float2 t = gather_pairs(srt + (size_t)k * E_ADJ, s, en, xk, lane);
    if (lane < 32) {
        f16x2 o;
        o.x = (f16)t.x;
        o.y = (f16)t.y;
        *(f16x2*)(agg + ((size_t)k * N_NODES + n) * HDIM + lane * 2) = o;
    }
}

// y_k = relu(agg_k @ W_k); h0 = y0+y1, h1 = y2+y3.
__global__ void gemm2(const f16* __restrict__ agg,   // [4][N][H] fp16
                      const float* __restrict__ W,   // [4][H][H]
                      f16* __restrict__ h0, f16* __restrict__ h1)
{
    const int wave = threadIdx.x >> 6;   // relation k
    const int lane = threadIdx.x & 63;   // h
    const int n0 = blockIdx.x * 8;       // 6250 blocks

    __shared__ float sg[4][8][HDIM];
    for (int i = threadIdx.x; i < 4 * 8 * HDIM; i += 256) {
        const int k = i >> 9, rem = i & 511;
        const int r = rem >> 6, f = rem & 63;
        sg[k][r][f] = (float)agg[((size_t)k * N_NODES + n0 + r) * HDIM + f];
    }
    __syncthreads();

    const float* Wk = W + (size_t)wave * HDIM * HDIM;
    float acc[8] = {0.f, 0.f, 0.f, 0.f, 0.f, 0.f, 0.f, 0.f};
#pragma unroll 4
    for (int f = 0; f < HDIM; ++f) {
        const float w = Wk[f * HDIM + lane];
#pragma unroll
        for (int r = 0; r < 8; ++r)
            acc[r] = fmaf(sg[wave][r][f], w, acc[r]);
    }
    __syncthreads();
#pragma unroll
    for (int r = 0; r < 8; ++r)
        sg[wave][r][lane] = fmaxf(acc[r], 0.f);
    __syncthreads();

    if (wave == 0) {
#pragma unroll
        for (int r = 0; r < 8; ++r)
            h0[(size_t)(n0 + r) * HDIM + lane] = (f16)(sg[0][r][lane] + sg[1][r][lane]);
    } else if (wave == 1) {
#pragma unroll
        for (int r = 0; r < 8; ++r)
            h1[(size_t)(n0 + r) * HDIM + lane] = (f16)(sg[2][r][lane] + sg[3][r][lane]);
    }
}

// ---------------------------------------------------------------------------
__global__ void make_M(const float* __restrict__ R, const float* __restrict__ Dl,
                       const int* __restrict__ rt_k, float* __restrict__ M)
{
    const int i = blockIdx.x * blockDim.x + threadIdx.x;
    if (i >= HDIM * HDIM) return;
    const float* d = Dl + rt_k[0] * HDIM;
    M[i] = d[i >> 6] * R[i] * d[i & 63];
}

// A[n][g] = sum_h h0[n][h] * M[h][g]   (fp16 out)
__global__ void h0M_kernel(const f16* __restrict__ h0, const float* __restrict__ M,
                           f16* __restrict__ A)
{
    const int wave = threadIdx.x >> 6, lane = threadIdx.x & 63;
    const int n0 = blockIdx.x * 16;      // 3125 blocks

    __shared__ float sx[16][HDIM];
    for (int i = threadIdx.x; i < 16 * HDIM; i += 256)
        sx[i >> 6][i & 63] = (float)h0[(size_t)n0 * HDIM + i];
    __syncthreads();

    float acc[4] = {0.f, 0.f, 0.f, 0.f};
#pragma unroll 4
    for (int f = 0; f < HDIM; ++f) {
        const float w = M[f * HDIM + lane];
#pragma unroll
        for (int r = 0; r < 4; ++r)
            acc[r] = fmaf(sx[wave * 4 + r][f], w, acc[r]);
    }
#pragma unroll
    for (int r = 0; r < 4; ++r)
        A[(size_t)(n0 + wave * 4 + r) * HDIM + lane] = (f16)acc[r];
}

// preds[e] = dot(A[i], h1[j])
__global__ void decode(const f16* __restrict__ A, const f16* __restrict__ h1,
                       const int* __restrict__ edges, float* __restrict__ out)
{
    const long long t = (long long)blockIdx.x * 256 + threadIdx.x;
    const int e = (int)(t >> 6);
    const int lane = (int)(t & 63);

    const int i = edges[2 * (size_t)e];
    const int j = edges[2 * (size_t)e + 1];

    float p = (float)A[(size_t)i * HDIM + lane] * (float)h1[(size_t)j * HDIM + lane];
#pragma unroll
    for (int off = 32; off; off >>= 1)
        p += __shfl_down(p, off, 64);
    if (lane == 0) out[e] = p;
}

// ---------------------------------------------------------------------------
static void build_csr(const int* rows, const int* cols, const float* vals,
                      int* gcur, int* srtbase, unsigned long long* bucketed,
                      float2* srt, int* row_ptr, hipStream_t stream)
{
    hipMemsetAsync(gcur, 0, 4 * NBUK * sizeof(int), stream);
    part_kernel<<<dim3(NPBLK, 4), 256, 0, stream>>>(rows, cols, vals, gcur, bucketed);
    bucket_scan<<<1, 64, 0, stream>>>(gcur, srtbase);
    bucket_sort<<<dim3(NBUK, 4), 256, 0, stream>>>(bucketed, gcur, srtbase, srt, row_ptr);
}

extern "C" void kernel_launch(void* const* d_in, const int* in_sizes, int n_in,
                              void* d_out, int out_size, void* d_ws, size_t ws_size,
                              hipStream_t stream) {
    const int*   adj_rows = (const int*)  d_in[0];
    const int*   adj_cols = (const int*)  d_in[1];
    const float* adj_vals = (const float*)d_in[2];
    const float* feat0    = (const float*)d_in[3];
    const float* feat1    = (const float*)d_in[4];
    const float* W1       = (const float*)d_in[5];
    const float* W2       = (const float*)d_in[6];
    const float* W3       = (const float*)d_in[7];
    const float* W4       = (const float*)d_in[8];
    const float* Rg       = (const float*)d_in[9];
    const float* Dl       = (const float*)d_in[10];
    const int*   edges    = (const int*)  d_in[11];
    const int*   rt_k     = (const int*)  d_in[12];
    float* out = (float*)d_out;

    const size_t NH = (size_t)N_NODES * HDIM;       // 3.2M
    float* ws = (float*)d_ws;
    // layout (float offsets):
    f16*    xwh     = (f16*)ws;                     // 4*NH halfs (table / agg / A)
    f16*    h0      = (f16*)(ws + 2 * NH);          // NH halfs
    f16*    h1      = (f16*)(ws + 2 * NH + NH / 2); // NH halfs
    float2* srt     = (float2*)(ws + 3 * NH);       // 4E float2 = 6.4M floats
    int*    row_ptr = (int*)(ws + 3 * NH + 8 * (size_t)E_ADJ); // 4*(N+1)
    int*    gcur    = row_ptr + 4 * NP1 + 60;       // 4*NBUK
    int*    srtbase = gcur + 4 * NBUK;              // 4*NBUK
    float*  M       = (float*)(srtbase + 4 * NBUK + 32);       // 4096 f
    unsigned long long* bucketed =
        (unsigned long long*)(M + HDIM * HDIM + 64);           // 4*NBUK*BCAP u64 = 32.1MB
    // y aliases bucketed: y live only in stage 1 (after build A, before build B).
    f16* y = (f16*)bucketed;                        // 4*NH halfs = 25.6MB < 32.1MB
    // total ~= 24.3M floats ~= 97.4 MB

    const int* r2 = adj_rows + 4 * (size_t)E_ADJ;
    const int* c2 = adj_cols + 4 * (size_t)E_ADJ;
    const float* v2 = adj_vals + 4 * (size_t)E_ADJ;

    // ---- CSR for adjacency group A (stages 1 & 2) ----
    build_csr(adj_rows, adj_cols, adj_vals, gcur, srtbase, bucketed, srt, row_ptr, stream);

    // ---- stage 1: transform-then-aggregate ----
    gemm_stage<FDIM><<<N_NODES / 8, 256, 0, stream>>>(feat0, feat1, W1, xwh);
    spmm_csr<<<N_NODES, 256, 0, stream>>>(srt, row_ptr, xwh, y);
    combine_kernel<<<(int)(NH / 2 / 256), 256, 0, stream>>>(y, h0, h1);

    // ---- stage 2: aggregate-then-transform ----
    agg_csr<<<N_NODES, 256, 0, stream>>>(srt, row_ptr, h0, h1, xwh);
    gemm2<<<N_NODES / 8, 256, 0, stream>>>(xwh, W2, h0, h1);

    // ---- CSR for adjacency group B (stages 3 & 4) ----
    build_csr(r2, c2, v2, gcur, srtbase, bucketed, srt, row_ptr, stream);

    // ---- stage 3 ----
    agg_csr<<<N_NODES, 256, 0, stream>>>(srt, row_ptr, h0, h1, xwh);
    gemm2<<<N_NODES / 8, 256, 0, stream>>>(xwh, W3, h0, h1);

    // ---- stage 4 ----
    agg_csr<<<N_NODES, 256, 0, stream>>>(srt, row_ptr, h0, h1, xwh);
    gemm2<<<N_NODES / 8, 256, 0, stream>>>(xwh, W4, h0, h1);

    // ---- decode: M, A = h0@M (fp16, aliases xwh), dot per edge ----
    make_M<<<(HDIM * HDIM + 255) / 256, 256, 0, stream>>>(Rg, Dl, rt_k, M);
    f16* A = xwh;
    h0M_kernel<<<N_NODES / 16, 256, 0, stream>>>(h0, M, A);
    decode<<<E_DEC * HDIM / 256, 256, 0, stream>>>(A, h1, edges, out);
}

// Round 15
// 619.835 us; speedup vs baseline: 5.3262x; 1.1917x over previous
//
#include <hip/hip_runtime.h>

#define N_NODES 50000
#define E_ADJ   800000
#define E_DEC   200000
#define FDIM    128
#define HDIM    64
#define NP1     (N_NODES + 1)
#define NBUK    196            // ceil(50000/256) buckets of 256 rows
#define BCAP    5120           // bucket capacity; mean 4082 -> 16-sigma margin
#define TILE_E  4096           // edges per part-block
#define EPB     16             // edges per thread
#define NPBLK   196            // ceil(E_ADJ/TILE_E)

typedef _Float16 f16;
typedef __attribute__((ext_vector_type(2))) _Float16 f16x2;
typedef __attribute__((ext_vector_type(4))) _Float16 f16x4;
typedef __attribute__((ext_vector_type(8))) _Float16 f16x8;
typedef __attribute__((ext_vector_type(4))) float f32x4;

__device__ __forceinline__ int   ntl_i(const int* p)   { return __builtin_nontemporal_load(p); }
__device__ __forceinline__ float ntl_f(const float* p) { return __builtin_nontemporal_load(p); }

// ---------------------------------------------------------------------------
// CSR build, two-level bucket sort (R11 structure, unchanged).
// ---------------------------------------------------------------------------
__global__ void part_kernel(const int* __restrict__ rows,
                            const int* __restrict__ cols,
                            const float* __restrict__ vals,
                            int* __restrict__ gcur,
                            unsigned long long* __restrict__ bucketed)
{
    const int k   = blockIdx.y;
    const int tid = threadIdx.x;
    const long long t0 = (long long)blockIdx.x * TILE_E;

    __shared__ int hist[NBUK];
    __shared__ int sbase[NBUK];
    for (int i = tid; i < NBUK; i += 256) hist[i] = 0;
    __syncthreads();

    int lidx[EPB];
    int brl[EPB];                       // packed (bucket<<8)|row_local
#pragma unroll
    for (int it = 0; it < EPB; ++it) {
        const long long e = t0 + it * 256 + tid;
        brl[it] = -1;
        if (e < E_ADJ) {
            const int r = ntl_i(&rows[(size_t)k * E_ADJ + e]);
            const int b = r >> 8;
            brl[it] = (b << 8) | (r & 255);
            lidx[it] = atomicAdd(&hist[b], 1);      // LDS atomic
        }
    }
    __syncthreads();

    for (int i = tid; i < NBUK; i += 256)
        sbase[i] = (hist[i] > 0) ? atomicAdd(&gcur[k * NBUK + i], hist[i]) : 0;
    __syncthreads();

#pragma unroll
    for (int it = 0; it < EPB; ++it) {
        if (brl[it] >= 0) {
            const long long e = t0 + it * 256 + tid;
            const int b  = brl[it] >> 8;
            const int rl = brl[it] & 255;
            const int c  = ntl_i(&cols[(size_t)k * E_ADJ + e]);
            const float v = ntl_f(&vals[(size_t)k * E_ADJ + e]);
            const unsigned meta = (unsigned)c | ((unsigned)rl << 16);   // col < 65536
            const unsigned long long payload =
                ((unsigned long long)__float_as_uint(v) << 32) | meta;
            bucketed[((size_t)(k * NBUK + b)) * BCAP + sbase[b] + lidx[it]] = payload;
        }
    }
}

__global__ void bucket_scan(const int* __restrict__ gcur, int* __restrict__ srtbase)
{
    const int k = threadIdx.x;
    if (k < 4) {
        int run = 0;
        for (int b = 0; b < NBUK; ++b) {
            srtbase[k * NBUK + b] = run;
            run += gcur[k * NBUK + b];
        }
    }
}

__global__ void bucket_sort(const unsigned long long* __restrict__ bucketed,
                            const int* __restrict__ gcur,
                            const int* __restrict__ srtbase,
                            float2* __restrict__ srt,
                            int* __restrict__ row_ptr)
{
    const int b = blockIdx.x, k = blockIdx.y, tid = threadIdx.x;
    const int cnt  = gcur[k * NBUK + b];
    const int base = srtbase[k * NBUK + b];
    const unsigned long long* bk = bucketed + (size_t)(k * NBUK + b) * BCAP;

    __shared__ int s[256];
    __shared__ int cur[256];
    __shared__ int rcnt[256];
    rcnt[tid] = 0;
    __syncthreads();

    for (int i = tid; i < cnt; i += 256) {
        const unsigned meta = (unsigned)bk[i];
        atomicAdd(&rcnt[(meta >> 16) & 255], 1);
    }
    __syncthreads();

    const int v = rcnt[tid];
    s[tid] = v;
    __syncthreads();
    for (int off = 1; off < 256; off <<= 1) {
        const int t = (tid >= off) ? s[tid - off] : 0;
        __syncthreads();
        s[tid] += t;
        __syncthreads();
    }
    const int excl = s[tid] - v;

    const int n = b * 256 + tid;
    if (n < N_NODES) row_ptr[k * NP1 + n] = base + excl;
    if (b == NBUK - 1 && tid == 0) row_ptr[k * NP1 + N_NODES] = E_ADJ;
    cur[tid] = base + excl;
    __syncthreads();

    for (int i = tid; i < cnt; i += 256) {
        const unsigned long long p = bk[i];
        const unsigned meta = (unsigned)p;
        const int rl = (meta >> 16) & 255;
        const int c  = meta & 0xFFFF;
        const float val = __uint_as_float((unsigned)(p >> 32));
        const int pos = atomicAdd(&cur[rl], 1);
        srt[(size_t)k * E_ADJ + pos] = make_float2(__int_as_float(c), val);
    }
}

// ---------------------------------------------------------------------------
// Paired-edge fp16x2 gather core (R13, unchanged).
// ---------------------------------------------------------------------------
__device__ __forceinline__ float2 gather_pairs(const float2* __restrict__ sp,
                                               int s, int en,
                                               const f16* __restrict__ xk,
                                               int lane)
{
    const int half = lane >> 5;
    const int hl   = lane & 31;
    float2 a0 = {0.f, 0.f}, a1 = {0.f, 0.f}, a2 = {0.f, 0.f}, a3 = {0.f, 0.f};

    for (int base = s; base < en; base += 64) {
        const int cnt = min(64, en - base);
        float2 meta = make_float2(0.f, 0.f);           // pad: col0/val0 is harmless
        if (lane < cnt) meta = sp[base + lane];
        const int npair = (cnt + 1) >> 1;
        int p = 0;
        for (; p + 4 <= npair; p += 4) {
            int c[4]; float v[4];
#pragma unroll
            for (int u = 0; u < 4; ++u) {
                const int sel = 2 * (p + u) + half;
                c[u] = __shfl(__float_as_int(meta.x), sel, 64);
                v[u] = __shfl(meta.y, sel, 64);
            }
            f16x2 g[4];
#pragma unroll
            for (int u = 0; u < 4; ++u)                // 4 independent 4B gathers
                g[u] = *(const f16x2*)(xk + (size_t)c[u] * HDIM + hl * 2);
            a0.x = fmaf((float)g[0].x, v[0], a0.x);
            a0.y = fmaf((float)g[0].y, v[0], a0.y);
            a1.x = fmaf((float)g[1].x, v[1], a1.x);
            a1.y = fmaf((float)g[1].y, v[1], a1.y);
            a2.x = fmaf((float)g[2].x, v[2], a2.x);
            a2.y = fmaf((float)g[2].y, v[2], a2.y);
            a3.x = fmaf((float)g[3].x, v[3], a3.x);
            a3.y = fmaf((float)g[3].y, v[3], a3.y);
        }
        for (; p < npair; ++p) {
            const int sel = 2 * p + half;
            const int cc = __shfl(__float_as_int(meta.x), sel, 64);
            const float vv = __shfl(meta.y, sel, 64);
            const f16x2 g = *(const f16x2*)(xk + (size_t)cc * HDIM + hl * 2);
            a0.x = fmaf((float)g.x, vv, a0.x);
            a0.y = fmaf((float)g.y, vv, a0.y);
        }
    }
    float2 t;
    t.x = (a0.x + a1.x) + (a2.x + a3.x);
    t.y = (a0.y + a1.y) + (a2.y + a3.y);
    t.x += __shfl(t.x, lane + 32, 64);   // combine odd/even-edge halves
    t.y += __shfl(t.y, lane + 32, 64);
    return t;                            // valid on lanes < 32
}

// ---------------------------------------------------------------------------
// W fragment pre-pack for mfma_f32_16x16x32_f16.
// B-frag layout: lane holds B[k=(lane>>4)*8+j + kc*32][col=nt*16+(lane&15)].
// out linear idx = ((((rel*4+nt)*kcs + kc)*64 + lane)*8 + j.
// ---------------------------------------------------------------------------
__global__ void pack_wfrag(const float* __restrict__ W, const int K,
                           f16* __restrict__ out)
{
    const int idx = blockIdx.x * 256 + threadIdx.x;
    const int j    = idx & 7;
    const int lane = (idx >> 3) & 63;
    const int kcs  = K >> 5;
    int rest = idx >> 9;
    const int kc  = rest % kcs; rest /= kcs;
    const int nt  = rest & 3;
    const int rel = rest >> 2;
    const int k   = kc * 32 + ((lane >> 4) * 8) + j;
    const int col = nt * 16 + (lane & 15);
    out[idx] = (f16)W[((size_t)rel * K + k) * HDIM + col];
}

// ---------------------------------------------------------------------------
// Stage-1 transform via MFMA: xw[k] = f16(xin_k[50000x128] @ W1_k[128x64]).
// Wave = relation; 2 row-tiles of 16 per wave; A from global fp32 (cvt f16),
// B from pre-packed frags (L1/L2-hot). C/D layout: col=lane&15,
// row=(lane>>4)*4+reg (m89-verified).
// ---------------------------------------------------------------------------
__global__ void gemm1_mfma(const float* __restrict__ x0,
                           const float* __restrict__ x1,
                           const f16* __restrict__ wf,   // [4][4][4][64][8]
                           f16* __restrict__ xw)         // [4][N][64]
{
    const int wave = threadIdx.x >> 6;   // relation
    const int lane = threadIdx.x & 63;
    const int n0 = blockIdx.x * 32;      // 1563 blocks cover 50016 (guarded)
    const int q = lane >> 4, r16 = lane & 15;

    const float* xr = (wave & 1) ? x1 : x0;

    f16x8 b[4][4];
#pragma unroll
    for (int nt = 0; nt < 4; ++nt)
#pragma unroll
        for (int kc = 0; kc < 4; ++kc)
            b[nt][kc] = *(const f16x8*)(wf + (((size_t)(wave * 4 + nt) * 4 + kc) * 64 + lane) * 8);

    for (int t = 0; t < 2; ++t) {
        const int row = n0 + t * 16 + r16;
        const int rowc = row < N_NODES ? row : N_NODES - 1;
        f16x8 a[4];
#pragma unroll
        for (int kc = 0; kc < 4; ++kc) {
            const float4 lo = *(const float4*)(xr + (size_t)rowc * FDIM + kc * 32 + q * 8);
            const float4 hi = *(const float4*)(xr + (size_t)rowc * FDIM + kc * 32 + q * 8 + 4);
            f16x8 av;
            av[0] = (f16)lo.x; av[1] = (f16)lo.y; av[2] = (f16)lo.z; av[3] = (f16)lo.w;
            av[4] = (f16)hi.x; av[5] = (f16)hi.y; av[6] = (f16)hi.z; av[7] = (f16)hi.w;
            a[kc] = av;
        }
#pragma unroll
        for (int nt = 0; nt < 4; ++nt) {
            f32x4 acc = {0.f, 0.f, 0.f, 0.f};
#pragma unroll
            for (int kc = 0; kc < 4; ++kc)
                acc = __builtin_amdgcn_mfma_f32_16x16x32_f16(a[kc], b[nt][kc], acc, 0, 0, 0);
#pragma unroll
            for (int j = 0; j < 4; ++j) {
                const int n = n0 + t * 16 + q * 4 + j;
                if (n < N_NODES)
                    xw[((size_t)wave * N_NODES + n) * HDIM + nt * 16 + r16] = (f16)acc[j];
            }
        }
    }
}

// ---------------------------------------------------------------------------
// Stages 2-4 transform via MFMA + fused relu + pairwise combine.
// y_k = relu(agg_k[50000x64] @ Wk[64x64]); h0 = y0+y1, h1 = y2+y3.
// ---------------------------------------------------------------------------
__global__ void gemm2_mfma(const f16* __restrict__ agg,  // [4][N][64]
                           const f16* __restrict__ wf,   // [4][4][2][64][8]
                           f16* __restrict__ h0, f16* __restrict__ h1)
{
    const int wave = threadIdx.x >> 6;
    const int lane = threadIdx.x & 63;
    const int tid  = threadIdx.x;
    const int n0 = blockIdx.x * 32;
    const int q = lane >> 4, r16 = lane & 15;

    f16x8 b[4][2];
#pragma unroll
    for (int nt = 0; nt < 4; ++nt)
#pragma unroll
        for (int kc = 0; kc < 2; ++kc)
            b[nt][kc] = *(const f16x8*)(wf + (((size_t)(wave * 4 + nt) * 2 + kc) * 64 + lane) * 8);

    __shared__ f16 yt[4][16][HDIM];

    for (int t = 0; t < 2; ++t) {
        const int row = n0 + t * 16 + r16;
        const int rowc = row < N_NODES ? row : N_NODES - 1;
        f16x8 a[2];
#pragma unroll
        for (int kc = 0; kc < 2; ++kc)
            a[kc] = *(const f16x8*)(agg + ((size_t)wave * N_NODES + rowc) * HDIM + kc * 32 + q * 8);

#pragma unroll
        for (int nt = 0; nt < 4; ++nt) {
            f32x4 acc = {0.f, 0.f, 0.f, 0.f};
#pragma unroll
            for (int kc = 0; kc < 2; ++kc)
                acc = __builtin_amdgcn_mfma_f32_16x16x32_f16(a[kc], b[nt][kc], acc, 0, 0, 0);
#pragma unroll
            for (int j = 0; j < 4; ++j)
                yt[wave][q * 4 + j][nt * 16 + r16] = (f16)fmaxf(acc[j], 0.f);
        }
        __syncthreads();

        // combine: h0 = y0+y1, h1 = y2+y3 (16 rows x 64 cols, f16x4 per thread)
        {
            const int r  = tid >> 4;          // 0..15
            const int c4 = (tid & 15) * 4;    // 0..60
            const int n  = n0 + t * 16 + r;
            if (n < N_NODES) {
                const f16x4 a0 = *(const f16x4*)&yt[0][r][c4];
                const f16x4 a1 = *(const f16x4*)&yt[1][r][c4];
                const f16x4 a2 = *(const f16x4*)&yt[2][r][c4];
                const f16x4 a3 = *(const f16x4*)&yt[3][r][c4];
                f16x4 o0, o1;
#pragma unroll
                for (int u = 0; u < 4; ++u) {
                    o0[u] = (f16)((float)a0[u] + (float)a1[u]);
                    o1[u] = (f16)((float)a2[u] + (float)a3[u]);
                }
                *(f16x4*)(h0 + (size_t)n * HDIM + c4) = o0;
                *(f16x4*)(h1 + (size_t)n * HDIM + c4) = o1;
            }
        }
        __syncthreads();
    }
}

// ---------------------------------------------------------------------------
// Stage-1 SPMM, relation-per-block + paired gathers (R13, unchanged).
// ---------------------------------------------------------------------------
__global__ void spmm_csr(const float2* __restrict__ srt,
                         const int*    __restrict__ row_ptr,
                         const f16*    __restrict__ xw,     // [4][N][H]
                         f16* __restrict__ y)               // [4][N][H] relu'd
{
    const int b = blockIdx.x, k = b & 3, g = b >> 2;        // 50000 blocks
    const int wave = threadIdx.x >> 6, lane = threadIdx.x & 63;
    const int n = g * 4 + wave;

    const int s  = row_ptr[k * NP1 + n];
    const int en = row_ptr[k * NP1 + n + 1];
    float2 t = gather_pairs(srt + (size_t)k * E_ADJ, s, en,
                            xw + (size_t)k * N_NODES * HDIM, lane);
    if (lane < 32) {
        f16x2 o;
        o.x = (f16)fmaxf(t.x, 0.f);
        o.y = (f16)fmaxf(t.y, 0.f);
        *(f16x2*)(y + ((size_t)k * N_NODES + n) * HDIM + lane * 2) = o;
    }
}

// h0 = y0+y1, h1 = y2+y3 (y already relu'd per relation).
__global__ void combine_kernel(const f16* __restrict__ y,
                               f16* __restrict__ h0, f16* __restrict__ h1)
{
    const size_t NHh = (size_t)N_NODES * HDIM / 2;
    const size_t i = (size_t)blockIdx.x * 256 + threadIdx.x;   // 6250 blocks exact
    const f16x2 a = ((const f16x2*)y)[i];
    const f16x2 b = ((const f16x2*)y)[NHh + i];
    const f16x2 c = ((const f16x2*)y)[2 * NHh + i];
    const f16x2 d = ((const f16x2*)y)[3 * NHh + i];
    f16x2 o0, o1;
    o0.x = (f16)((float)a.x + (float)b.x);
    o0.y = (f16)((float)a.y + (float)b.y);
    o1.x = (f16)((float)c.x + (float)d.x);
    o1.y = (f16)((float)c.y + (float)d.y);
    ((f16x2*)h0)[i] = o0;
    ((f16x2*)h1)[i] = o1;
}

// ---------------------------------------------------------------------------
// Stages 2-4 aggregate, relation-per-block (R13, unchanged).
// ---------------------------------------------------------------------------
__global__ void agg_csr(const float2* __restrict__ srt,
                        const int*    __restrict__ row_ptr,
                        const f16*    __restrict__ h0,
                        const f16*    __restrict__ h1,
                        f16* __restrict__ agg)    // [4][N][H]
{
    const int b = blockIdx.x, k = b & 3, g = b >> 2;        // 50000 blocks
    const int wave = threadIdx.x >> 6, lane = threadIdx.x & 63;
    const int n = g * 4 + wave;

    const int s  = row_ptr[k * NP1 + n];
    const int en = row_ptr[k * NP1 + n + 1];
    const f16* xk = (k & 1) ? h1 : h0;
    float2 t = gather_pairs(srt + (size_t)k * E_ADJ, s, en, xk, lane);
    if (lane < 32) {
        f16x2 o;
        o.x = (f16)t.x;
        o.y = (f16)t.y;
        *(f16x2*)(agg + ((size_t)k * N_NODES + n) * HDIM + lane * 2) = o;
    }
}

// ---------------------------------------------------------------------------
__global__ void make_M(const float* __restrict__ R, const float* __restrict__ Dl,
                       const int* __restrict__ rt_k, float* __restrict__ M)
{
    const int i = blockIdx.x * blockDim.x + threadIdx.x;
    if (i >= HDIM * HDIM) return;
    const float* d = Dl + rt_k[0] * HDIM;
    M[i] = d[i >> 6] * R[i] * d[i & 63];
}

// A[n][g] = sum_h h0[n][h] * M[h][g]   (fp16 out)
__global__ void h0M_kernel(const f16* __restrict__ h0, const float* __restrict__ M,
                           f16* __restrict__ A)
{
    const int wave = threadIdx.x >> 6, lane = threadIdx.x & 63;
    const int n0 = blockIdx.x * 16;      // 3125 blocks

    __shared__ float sx[16][HDIM];
    for (int i = threadIdx.x; i < 16 * HDIM; i += 256)
        sx[i >> 6][i & 63] = (float)h0[(size_t)n0 * HDIM + i];
    __syncthreads();

    float acc[4] = {0.f, 0.f, 0.f, 0.f};
#pragma unroll 4
    for (int f = 0; f < HDIM; ++f) {
        const float w = M[f * HDIM + lane];
#pragma unroll
        for (int r = 0; r < 4; ++r)
            acc[r] = fmaf(sx[wave * 4 + r][f], w, acc[r]);
    }
#pragma unroll
    for (int r = 0; r < 4; ++r)
        A[(size_t)(n0 + wave * 4 + r) * HDIM + lane] = (f16)acc[r];
}

// preds[e] = dot(A[i], h1[j])
__global__ void decode(const f16* __restrict__ A, const f16* __restrict__ h1,
                       const int* __restrict__ edges, float* __restrict__ out)
{
    const long long t = (long long)blockIdx.x * 256 + threadIdx.x;
    const int e = (int)(t >> 6);
    const int lane = (int)(t & 63);

    const int i = edges[2 * (size_t)e];
    const int j = edges[2 * (size_t)e + 1];

    float p = (float)A[(size_t)i * HDIM + lane] * (float)h1[(size_t)j * HDIM + lane];
#pragma unroll
    for (int off = 32; off; off >>= 1)
        p += __shfl_down(p, off, 64);
    if (lane == 0) out[e] = p;
}

// ---------------------------------------------------------------------------
static void build_csr(const int* rows, const int* cols, const float* vals,
                      int* gcur, int* srtbase, unsigned long long* bucketed,
                      float2* srt, int* row_ptr, hipStream_t stream)
{
    hipMemsetAsync(gcur, 0, 4 * NBUK * sizeof(int), stream);
    part_kernel<<<dim3(NPBLK, 4), 256, 0, stream>>>(rows, cols, vals, gcur, bucketed);
    bucket_scan<<<1, 64, 0, stream>>>(gcur, srtbase);
    bucket_sort<<<dim3(NBUK, 4), 256, 0, stream>>>(bucketed, gcur, srtbase, srt, row_ptr);
}

extern "C" void kernel_launch(void* const* d_in, const int* in_sizes, int n_in,
                              void* d_out, int out_size, void* d_ws, size_t ws_size,
                              hipStream_t stream) {
    const int*   adj_rows = (const int*)  d_in[0];
    const int*   adj_cols = (const int*)  d_in[1];
    const float* adj_vals = (const float*)d_in[2];
    const float* feat0    = (const float*)d_in[3];
    const float* feat1    = (const float*)d_in[4];
    const float* W1       = (const float*)d_in[5];
    const float* W2       = (const float*)d_in[6];
    const float* W3       = (const float*)d_in[7];
    const float* W4       = (const float*)d_in[8];
    const float* Rg       = (const float*)d_in[9];
    const float* Dl       = (const float*)d_in[10];
    const int*   edges    = (const int*)  d_in[11];
    const int*   rt_k     = (const int*)  d_in[12];
    float* out = (float*)d_out;

    const size_t NH = (size_t)N_NODES * HDIM;       // 3.2M
    float* ws = (float*)d_ws;
    // layout (float offsets):
    f16*    xwh     = (f16*)ws;                     // 4*NH halfs (table / agg / A)
    f16*    h0      = (f16*)(ws + 2 * NH);          // NH halfs
    f16*    h1      = (f16*)(ws + 2 * NH + NH / 2); // NH halfs
    float2* srt     = (float2*)(ws + 3 * NH);       // 4E float2 = 6.4M floats
    int*    row_ptr = (int*)(ws + 3 * NH + 8 * (size_t)E_ADJ); // 4*(N+1)
    int*    gcur    = row_ptr + 4 * NP1 + 60;       // 4*NBUK
    int*    srtbase = gcur + 4 * NBUK;              // 4*NBUK
    float*  M       = (float*)(srtbase + 4 * NBUK + 32);       // 4096 f
    unsigned long long* bucketed =
        (unsigned long long*)(M + HDIM * HDIM + 64);           // 4*NBUK*BCAP u64 = 32.1MB
    // y aliases bucketed: y live only in stage 1 (after build A, before build B).
    f16* y = (f16*)bucketed;                        // 4*NH halfs = 25.6MB < 32.1MB
    // W fragment tables after bucketed: 4*4*4*512 + 3*(4*4*2*512) = 81920 f16 = 160KB
    f16* wfrag = (f16*)(bucketed + (size_t)4 * NBUK * BCAP);
    f16* wf1 = wfrag;            // 32768 f16
    f16* wf2 = wfrag + 32768;    // 16384 f16
    f16* wf3 = wfrag + 49152;    // 16384 f16
    f16* wf4 = wfrag + 65536;    // 16384 f16
    // total ~= 24.3M floats ~= 97.5 MB

    const int* r2 = adj_rows + 4 * (size_t)E_ADJ;
    const int* c2 = adj_cols + 4 * (size_t)E_ADJ;
    const float* v2 = adj_vals + 4 * (size_t)E_ADJ;

    // ---- pre-pack W fragments (independent of pipeline) ----
    pack_wfrag<<<128, 256, 0, stream>>>(W1, FDIM, wf1);
    pack_wfrag<<<64, 256, 0, stream>>>(W2, HDIM, wf2);
    pack_wfrag<<<64, 256, 0, stream>>>(W3, HDIM, wf3);
    pack_wfrag<<<64, 256, 0, stream>>>(W4, HDIM, wf4);

    // ---- CSR for adjacency group A (stages 1 & 2) ----
    build_csr(adj_rows, adj_cols, adj_vals, gcur, srtbase, bucketed, srt, row_ptr, stream);

    // ---- stage 1: transform (MFMA) then aggregate ----
    gemm1_mfma<<<1563, 256, 0, stream>>>(feat0, feat1, wf1, xwh);
    spmm_csr<<<N_NODES, 256, 0, stream>>>(srt, row_ptr, xwh, y);
    combine_kernel<<<(int)(NH / 2 / 256), 256, 0, stream>>>(y, h0, h1);

    // ---- stage 2: aggregate then transform (MFMA) ----
    agg_csr<<<N_NODES, 256, 0, stream>>>(srt, row_ptr, h0, h1, xwh);
    gemm2_mfma<<<1563, 256, 0, stream>>>(xwh, wf2, h0, h1);

    // ---- CSR for adjacency group B (stages 3 & 4) ----
    build_csr(r2, c2, v2, gcur, srtbase, bucketed, srt, row_ptr, stream);

    // ---- stage 3 ----
    agg_csr<<<N_NODES, 256, 0, stream>>>(srt, row_ptr, h0, h1, xwh);
    gemm2_mfma<<<1563, 256, 0, stream>>>(xwh, wf3, h0, h1);

    // ---- stage 4 ----
    agg_csr<<<N_NODES, 256, 0, stream>>>(srt, row_ptr, h0, h1, xwh);
    gemm2_mfma<<<1563, 256, 0, stream>>>(xwh, wf4, h0, h1);

    // ---- decode: M, A = h0@M (fp16, aliases xwh), dot per edge ----
    make_M<<<(HDIM * HDIM + 255) / 256, 256, 0, stream>>>(Rg, Dl, rt_k, M);
    f16* A = xwh;
    h0M_kernel<<<N_NODES / 16, 256, 0, stream>>>(h0, M, A);
    decode<<<E_DEC * HDIM / 256, 256, 0, stream>>>(A, h1, edges, out);
}

// Round 16
// 541.302 us; speedup vs baseline: 6.0989x; 1.1451x over previous
//
#include <hip/hip_runtime.h>

#define N_NODES 50000
#define E_ADJ   800000
#define E_DEC   200000
#define FDIM    128
#define HDIM    64
#define NP1     (N_NODES + 1)
#define NBUK    196            // ceil(50000/256) buckets of 256 rows
#define BCAP    5120           // bucket capacity; mean 4082 -> 16-sigma margin
#define TILE_E  4096           // edges per part-block
#define EPB     16             // edges per thread
#define NPBLK   196            // ceil(E_ADJ/TILE_E)

typedef _Float16 f16;
typedef __attribute__((ext_vector_type(2))) _Float16 f16x2;
typedef __attribute__((ext_vector_type(4))) _Float16 f16x4;
typedef __attribute__((ext_vector_type(8))) _Float16 f16x8;
typedef __attribute__((ext_vector_type(4))) float f32x4;

__device__ __forceinline__ int   ntl_i(const int* p)   { return __builtin_nontemporal_load(p); }
__device__ __forceinline__ float ntl_f(const float* p) { return __builtin_nontemporal_load(p); }

// ---------------------------------------------------------------------------
// CSR build, two-level bucket sort (R11 structure).
// ---------------------------------------------------------------------------
__global__ void part_kernel(const int* __restrict__ rows,
                            const int* __restrict__ cols,
                            const float* __restrict__ vals,
                            int* __restrict__ gcur,
                            unsigned long long* __restrict__ bucketed)
{
    const int k   = blockIdx.y;
    const int tid = threadIdx.x;
    const long long t0 = (long long)blockIdx.x * TILE_E;

    __shared__ int hist[NBUK];
    __shared__ int sbase[NBUK];
    for (int i = tid; i < NBUK; i += 256) hist[i] = 0;
    __syncthreads();

    int lidx[EPB];
    int brl[EPB];                       // packed (bucket<<8)|row_local
#pragma unroll
    for (int it = 0; it < EPB; ++it) {
        const long long e = t0 + it * 256 + tid;
        brl[it] = -1;
        if (e < E_ADJ) {
            const int r = ntl_i(&rows[(size_t)k * E_ADJ + e]);
            const int b = r >> 8;
            brl[it] = (b << 8) | (r & 255);
            lidx[it] = atomicAdd(&hist[b], 1);      // LDS atomic
        }
    }
    __syncthreads();

    for (int i = tid; i < NBUK; i += 256)
        sbase[i] = (hist[i] > 0) ? atomicAdd(&gcur[k * NBUK + i], hist[i]) : 0;
    __syncthreads();

#pragma unroll
    for (int it = 0; it < EPB; ++it) {
        if (brl[it] >= 0) {
            const long long e = t0 + it * 256 + tid;
            const int b  = brl[it] >> 8;
            const int rl = brl[it] & 255;
            const int c  = ntl_i(&cols[(size_t)k * E_ADJ + e]);
            const float v = ntl_f(&vals[(size_t)k * E_ADJ + e]);
            const unsigned meta = (unsigned)c | ((unsigned)rl << 16);   // col < 65536
            const unsigned long long payload =
                ((unsigned long long)__float_as_uint(v) << 32) | meta;
            bucketed[((size_t)(k * NBUK + b)) * BCAP + sbase[b] + lidx[it]] = payload;
        }
    }
}

__global__ void bucket_scan(const int* __restrict__ gcur, int* __restrict__ srtbase)
{
    const int k = threadIdx.x;
    if (k < 4) {
        int run = 0;
        for (int b = 0; b < NBUK; ++b) {
            srtbase[k * NBUK + b] = run;
            run += gcur[k * NBUK + b];
        }
    }
}

// srt entry: {val_f16 << 16 | col_u16} — halves the meta stream and makes the
// broadcast a single shuffle.
__global__ void bucket_sort(const unsigned long long* __restrict__ bucketed,
                            const int* __restrict__ gcur,
                            const int* __restrict__ srtbase,
                            unsigned* __restrict__ srt,
                            int* __restrict__ row_ptr)
{
    const int b = blockIdx.x, k = blockIdx.y, tid = threadIdx.x;
    const int cnt  = gcur[k * NBUK + b];
    const int base = srtbase[k * NBUK + b];
    const unsigned long long* bk = bucketed + (size_t)(k * NBUK + b) * BCAP;

    __shared__ int s[256];
    __shared__ int cur[256];
    __shared__ int rcnt[256];
    rcnt[tid] = 0;
    __syncthreads();

    for (int i = tid; i < cnt; i += 256) {
        const unsigned meta = (unsigned)bk[i];
        atomicAdd(&rcnt[(meta >> 16) & 255], 1);
    }
    __syncthreads();

    const int v = rcnt[tid];
    s[tid] = v;
    __syncthreads();
    for (int off = 1; off < 256; off <<= 1) {
        const int t = (tid >= off) ? s[tid - off] : 0;
        __syncthreads();
        s[tid] += t;
        __syncthreads();
    }
    const int excl = s[tid] - v;

    const int n = b * 256 + tid;
    if (n < N_NODES) row_ptr[k * NP1 + n] = base + excl;
    if (b == NBUK - 1 && tid == 0) row_ptr[k * NP1 + N_NODES] = E_ADJ;
    cur[tid] = base + excl;
    __syncthreads();

    for (int i = tid; i < cnt; i += 256) {
        const unsigned long long p = bk[i];
        const unsigned meta = (unsigned)p;
        const int rl = (meta >> 16) & 255;
        const int c  = meta & 0xFFFF;
        const float val = __uint_as_float((unsigned)(p >> 32));
        union { f16 h; unsigned short us; } cv;
        cv.h = (f16)val;
        const int pos = atomicAdd(&cur[rl], 1);
        srt[(size_t)k * E_ADJ + pos] = ((unsigned)cv.us << 16) | (unsigned)c;
    }
}

// ---------------------------------------------------------------------------
// f16x4 quad gather core: lane covers h=(lane&15)*4..+3 (8B loads); edge slot
// es=lane>>4 -> 4 edges in flight per iteration; meta = 1 shuffle per edge.
// Zero-padded meta (col 0, val 0) makes tails branch-free. Final xor-reduce
// over es-groups (2 rounds). Result valid on lanes 0-15.
// ---------------------------------------------------------------------------
__device__ __forceinline__ void gather_quads(const unsigned* __restrict__ sp,
                                             int s, int en,
                                             const f16* __restrict__ xk,
                                             int lane, float a[4])
{
    const int es = lane >> 4;
    const int hb = (lane & 15) * 4;

    for (int base = s; base < en; base += 64) {
        const int cnt = min(64, en - base);
        unsigned meta = 0;
        if (lane < cnt) meta = sp[base + lane];
        const int nq = (cnt + 3) >> 2;
        int p = 0;
        for (; p + 4 <= nq; p += 4) {
            unsigned m[4];
#pragma unroll
            for (int u = 0; u < 4; ++u)
                m[u] = __shfl(meta, (p + u) * 4 + es, 64);
            f16x4 g[4];
            float v[4];
#pragma unroll
            for (int u = 0; u < 4; ++u) {
                union { unsigned short us; f16 h; } cv;
                cv.us = (unsigned short)(m[u] >> 16);
                v[u] = (float)cv.h;
                g[u] = *(const f16x4*)(xk + (size_t)(m[u] & 0xFFFF) * HDIM + hb);
            }
#pragma unroll
            for (int u = 0; u < 4; ++u) {
                a[0] = fmaf((float)g[u][0], v[u], a[0]);
                a[1] = fmaf((float)g[u][1], v[u], a[1]);
                a[2] = fmaf((float)g[u][2], v[u], a[2]);
                a[3] = fmaf((float)g[u][3], v[u], a[3]);
            }
        }
        for (; p < nq; ++p) {
            const unsigned m = __shfl(meta, p * 4 + es, 64);
            union { unsigned short us; f16 h; } cv;
            cv.us = (unsigned short)(m >> 16);
            const float v = (float)cv.h;
            const f16x4 g = *(const f16x4*)(xk + (size_t)(m & 0xFFFF) * HDIM + hb);
            a[0] = fmaf((float)g[0], v, a[0]);
            a[1] = fmaf((float)g[1], v, a[1]);
            a[2] = fmaf((float)g[2], v, a[2]);
            a[3] = fmaf((float)g[3], v, a[3]);
        }
    }
#pragma unroll
    for (int j = 0; j < 4; ++j) {
        a[j] += __shfl_xor(a[j], 16, 64);
        a[j] += __shfl_xor(a[j], 32, 64);
    }
}

// ---------------------------------------------------------------------------
// W fragment pre-pack for mfma_f32_16x16x32_f16 (R15, unchanged).
// ---------------------------------------------------------------------------
__global__ void pack_wfrag(const float* __restrict__ W, const int K,
                           f16* __restrict__ out)
{
    const int idx = blockIdx.x * 256 + threadIdx.x;
    const int j    = idx & 7;
    const int lane = (idx >> 3) & 63;
    const int kcs  = K >> 5;
    int rest = idx >> 9;
    const int kc  = rest % kcs; rest /= kcs;
    const int nt  = rest & 3;
    const int rel = rest >> 2;
    const int k   = kc * 32 + ((lane >> 4) * 8) + j;
    const int col = nt * 16 + (lane & 15);
    out[idx] = (f16)W[((size_t)rel * K + k) * HDIM + col];
}

// ---------------------------------------------------------------------------
// Stage-1 transform via MFMA (R15, unchanged).
// ---------------------------------------------------------------------------
__global__ void gemm1_mfma(const float* __restrict__ x0,
                           const float* __restrict__ x1,
                           const f16* __restrict__ wf,   // [4][4][4][64][8]
                           f16* __restrict__ xw)         // [4][N][64]
{
    const int wave = threadIdx.x >> 6;   // relation
    const int lane = threadIdx.x & 63;
    const int n0 = blockIdx.x * 32;      // 1563 blocks cover 50016 (guarded)
    const int q = lane >> 4, r16 = lane & 15;

    const float* xr = (wave & 1) ? x1 : x0;

    f16x8 b[4][4];
#pragma unroll
    for (int nt = 0; nt < 4; ++nt)
#pragma unroll
        for (int kc = 0; kc < 4; ++kc)
            b[nt][kc] = *(const f16x8*)(wf + (((size_t)(wave * 4 + nt) * 4 + kc) * 64 + lane) * 8);

    for (int t = 0; t < 2; ++t) {
        const int row = n0 + t * 16 + r16;
        const int rowc = row < N_NODES ? row : N_NODES - 1;
        f16x8 a[4];
#pragma unroll
        for (int kc = 0; kc < 4; ++kc) {
            const float4 lo = *(const float4*)(xr + (size_t)rowc * FDIM + kc * 32 + q * 8);
            const float4 hi = *(const float4*)(xr + (size_t)rowc * FDIM + kc * 32 + q * 8 + 4);
            f16x8 av;
            av[0] = (f16)lo.x; av[1] = (f16)lo.y; av[2] = (f16)lo.z; av[3] = (f16)lo.w;
            av[4] = (f16)hi.x; av[5] = (f16)hi.y; av[6] = (f16)hi.z; av[7] = (f16)hi.w;
            a[kc] = av;
        }
#pragma unroll
        for (int nt = 0; nt < 4; ++nt) {
            f32x4 acc = {0.f, 0.f, 0.f, 0.f};
#pragma unroll
            for (int kc = 0; kc < 4; ++kc)
                acc = __builtin_amdgcn_mfma_f32_16x16x32_f16(a[kc], b[nt][kc], acc, 0, 0, 0);
#pragma unroll
            for (int j = 0; j < 4; ++j) {
                const int n = n0 + t * 16 + q * 4 + j;
                if (n < N_NODES)
                    xw[((size_t)wave * N_NODES + n) * HDIM + nt * 16 + r16] = (f16)acc[j];
            }
        }
    }
}

// ---------------------------------------------------------------------------
// Stages 2-4 transform via MFMA + fused relu + pairwise combine (R15).
// ---------------------------------------------------------------------------
__global__ void gemm2_mfma(const f16* __restrict__ agg,  // [4][N][64]
                           const f16* __restrict__ wf,   // [4][4][2][64][8]
                           f16* __restrict__ h0, f16* __restrict__ h1)
{
    const int wave = threadIdx.x >> 6;
    const int lane = threadIdx.x & 63;
    const int tid  = threadIdx.x;
    const int n0 = blockIdx.x * 32;
    const int q = lane >> 4, r16 = lane & 15;

    f16x8 b[4][2];
#pragma unroll
    for (int nt = 0; nt < 4; ++nt)
#pragma unroll
        for (int kc = 0; kc < 2; ++kc)
            b[nt][kc] = *(const f16x8*)(wf + (((size_t)(wave * 4 + nt) * 2 + kc) * 64 + lane) * 8);

    __shared__ f16 yt[4][16][HDIM];

    for (int t = 0; t < 2; ++t) {
        const int row = n0 + t * 16 + r16;
        const int rowc = row < N_NODES ? row : N_NODES - 1;
        f16x8 a[2];
#pragma unroll
        for (int kc = 0; kc < 2; ++kc)
            a[kc] = *(const f16x8*)(agg + ((size_t)wave * N_NODES + rowc) * HDIM + kc * 32 + q * 8);

#pragma unroll
        for (int nt = 0; nt < 4; ++nt) {
            f32x4 acc = {0.f, 0.f, 0.f, 0.f};
#pragma unroll
            for (int kc = 0; kc < 2; ++kc)
                acc = __builtin_amdgcn_mfma_f32_16x16x32_f16(a[kc], b[nt][kc], acc, 0, 0, 0);
#pragma unroll
            for (int j = 0; j < 4; ++j)
                yt[wave][q * 4 + j][nt * 16 + r16] = (f16)fmaxf(acc[j], 0.f);
        }
        __syncthreads();

        {
            const int r  = tid >> 4;          // 0..15
            const int c4 = (tid & 15) * 4;    // 0..60
            const int n  = n0 + t * 16 + r;
            if (n < N_NODES) {
                const f16x4 a0 = *(const f16x4*)&yt[0][r][c4];
                const f16x4 a1 = *(const f16x4*)&yt[1][r][c4];
                const f16x4 a2 = *(const f16x4*)&yt[2][r][c4];
                const f16x4 a3 = *(const f16x4*)&yt[3][r][c4];
                f16x4 o0, o1;
#pragma unroll
                for (int u = 0; u < 4; ++u) {
                    o0[u] = (f16)((float)a0[u] + (float)a1[u]);
                    o1[u] = (f16)((float)a2[u] + (float)a3[u]);
                }
                *(f16x4*)(h0 + (size_t)n * HDIM + c4) = o0;
                *(f16x4*)(h1 + (size_t)n * HDIM + c4) = o1;
            }
        }
        __syncthreads();
    }
}

// ---------------------------------------------------------------------------
// Stage-1 SPMM, relation-per-block + quad gathers.
// ---------------------------------------------------------------------------
__global__ void spmm_csr(const unsigned* __restrict__ srt,
                         const int*    __restrict__ row_ptr,
                         const f16*    __restrict__ xw,     // [4][N][H]
                         f16* __restrict__ y)               // [4][N][H] relu'd
{
    const int b = blockIdx.x, k = b & 3, g = b >> 2;        // 50000 blocks
    const int wave = threadIdx.x >> 6, lane = threadIdx.x & 63;
    const int n = g * 4 + wave;

    const int s  = row_ptr[k * NP1 + n];
    const int en = row_ptr[k * NP1 + n + 1];
    float a[4] = {0.f, 0.f, 0.f, 0.f};
    gather_quads(srt + (size_t)k * E_ADJ, s, en,
                 xw + (size_t)k * N_NODES * HDIM, lane, a);
    if (lane < 16) {
        f16x4 o;
        o[0] = (f16)fmaxf(a[0], 0.f);
        o[1] = (f16)fmaxf(a[1], 0.f);
        o[2] = (f16)fmaxf(a[2], 0.f);
        o[3] = (f16)fmaxf(a[3], 0.f);
        *(f16x4*)(y + ((size_t)k * N_NODES + n) * HDIM + lane * 4) = o;
    }
}

// h0 = y0+y1, h1 = y2+y3 (y already relu'd per relation).
__global__ void combine_kernel(const f16* __restrict__ y,
                               f16* __restrict__ h0, f16* __restrict__ h1)
{
    const size_t NHh = (size_t)N_NODES * HDIM / 2;
    const size_t i = (size_t)blockIdx.x * 256 + threadIdx.x;   // 6250 blocks exact
    const f16x2 a = ((const f16x2*)y)[i];
    const f16x2 b = ((const f16x2*)y)[NHh + i];
    const f16x2 c = ((const f16x2*)y)[2 * NHh + i];
    const f16x2 d = ((const f16x2*)y)[3 * NHh + i];
    f16x2 o0, o1;
    o0.x = (f16)((float)a.x + (float)b.x);
    o0.y = (f16)((float)a.y + (float)b.y);
    o1.x = (f16)((float)c.x + (float)d.x);
    o1.y = (f16)((float)c.y + (float)d.y);
    ((f16x2*)h0)[i] = o0;
    ((f16x2*)h1)[i] = o1;
}

// ---------------------------------------------------------------------------
// Stages 2-4 aggregate, relation-per-block + quad gathers.
// ---------------------------------------------------------------------------
__global__ void agg_csr(const unsigned* __restrict__ srt,
                        const int*    __restrict__ row_ptr,
                        const f16*    __restrict__ h0,
                        const f16*    __restrict__ h1,
                        f16* __restrict__ agg)    // [4][N][H]
{
    const int b = blockIdx.x, k = b & 3, g = b >> 2;        // 50000 blocks
    const int wave = threadIdx.x >> 6, lane = threadIdx.x & 63;
    const int n = g * 4 + wave;

    const int s  = row_ptr[k * NP1 + n];
    const int en = row_ptr[k * NP1 + n + 1];
    const f16* xk = (k & 1) ? h1 : h0;
    float a[4] = {0.f, 0.f, 0.f, 0.f};
    gather_quads(srt + (size_t)k * E_ADJ, s, en, xk, lane, a);
    if (lane < 16) {
        f16x4 o;
        o[0] = (f16)a[0];
        o[1] = (f16)a[1];
        o[2] = (f16)a[2];
        o[3] = (f16)a[3];
        *(f16x4*)(agg + ((size_t)k * N_NODES + n) * HDIM + lane * 4) = o;
    }
}

// ---------------------------------------------------------------------------
__global__ void make_M(const float* __restrict__ R, const float* __restrict__ Dl,
                       const int* __restrict__ rt_k, float* __restrict__ M)
{
    const int i = blockIdx.x * blockDim.x + threadIdx.x;
    if (i >= HDIM * HDIM) return;
    const float* d = Dl + rt_k[0] * HDIM;
    M[i] = d[i >> 6] * R[i] * d[i & 63];
}

// A[n][g] = sum_h h0[n][h] * M[h][g]   (fp16 out)
__global__ void h0M_kernel(const f16* __restrict__ h0, const float* __restrict__ M,
                           f16* __restrict__ A)
{
    const int wave = threadIdx.x >> 6, lane = threadIdx.x & 63;
    const int n0 = blockIdx.x * 16;      // 3125 blocks

    __shared__ float sx[16][HDIM];
    for (int i = threadIdx.x; i < 16 * HDIM; i += 256)
        sx[i >> 6][i & 63] = (float)h0[(size_t)n0 * HDIM + i];
    __syncthreads();

    float acc[4] = {0.f, 0.f, 0.f, 0.f};
#pragma unroll 4
    for (int f = 0; f < HDIM; ++f) {
        const float w = M[f * HDIM + lane];
#pragma unroll
        for (int r = 0; r < 4; ++r)
            acc[r] = fmaf(sx[wave * 4 + r][f], w, acc[r]);
    }
#pragma unroll
    for (int r = 0; r < 4; ++r)
        A[(size_t)(n0 + wave * 4 + r) * HDIM + lane] = (f16)acc[r];
}

// preds[e] = dot(A[i], h1[j]) — 4 edges/wave, f16x4 (8B) loads, 4-round reduce.
__global__ void decode(const f16* __restrict__ A, const f16* __restrict__ h1,
                       const int* __restrict__ edges, float* __restrict__ out)
{
    const int w = (blockIdx.x * 256 + threadIdx.x) >> 6;   // 12500 blocks -> 50000 waves
    const int lane = threadIdx.x & 63;
    const int e = w * 4 + (lane >> 4);                     // 4 edges per wave
    const int q = lane & 15;

    const int i = edges[2 * (size_t)e];
    const int j = edges[2 * (size_t)e + 1];

    const f16x4 a = *(const f16x4*)(A + (size_t)i * HDIM + q * 4);
    const f16x4 b = *(const f16x4*)(h1 + (size_t)j * HDIM + q * 4);
    float p = 0.f;
#pragma unroll
    for (int u = 0; u < 4; ++u)
        p = fmaf((float)a[u], (float)b[u], p);
    p += __shfl_xor(p, 1, 64);
    p += __shfl_xor(p, 2, 64);
    p += __shfl_xor(p, 4, 64);
    p += __shfl_xor(p, 8, 64);
    if (q == 0) out[e] = p;
}

// ---------------------------------------------------------------------------
static void build_csr(const int* rows, const int* cols, const float* vals,
                      int* gcur, int* srtbase, unsigned long long* bucketed,
                      unsigned* srt, int* row_ptr, hipStream_t stream)
{
    hipMemsetAsync(gcur, 0, 4 * NBUK * sizeof(int), stream);
    part_kernel<<<dim3(NPBLK, 4), 256, 0, stream>>>(rows, cols, vals, gcur, bucketed);
    bucket_scan<<<1, 64, 0, stream>>>(gcur, srtbase);
    bucket_sort<<<dim3(NBUK, 4), 256, 0, stream>>>(bucketed, gcur, srtbase, srt, row_ptr);
}

extern "C" void kernel_launch(void* const* d_in, const int* in_sizes, int n_in,
                              void* d_out, int out_size, void* d_ws, size_t ws_size,
                              hipStream_t stream) {
    const int*   adj_rows = (const int*)  d_in[0];
    const int*   adj_cols = (const int*)  d_in[1];
    const float* adj_vals = (const float*)d_in[2];
    const float* feat0    = (const float*)d_in[3];
    const float* feat1    = (const float*)d_in[4];
    const float* W1       = (const float*)d_in[5];
    const float* W2       = (const float*)d_in[6];
    const float* W3       = (const float*)d_in[7];
    const float* W4       = (const float*)d_in[8];
    const float* Rg       = (const float*)d_in[9];
    const float* Dl       = (const float*)d_in[10];
    const int*   edges    = (const int*)  d_in[11];
    const int*   rt_k     = (const int*)  d_in[12];
    float* out = (float*)d_out;

    const size_t NH = (size_t)N_NODES * HDIM;       // 3.2M
    float* ws = (float*)d_ws;
    // layout (float offsets):
    f16*      xwh     = (f16*)ws;                     // 4*NH halfs (table / agg / A)
    f16*      h0      = (f16*)(ws + 2 * NH);          // NH halfs
    f16*      h1      = (f16*)(ws + 2 * NH + NH / 2); // NH halfs
    unsigned* srt     = (unsigned*)(ws + 3 * NH);     // 4E u32 (12.8MB; region has 6.4M floats)
    int*      row_ptr = (int*)(ws + 3 * NH + 8 * (size_t)E_ADJ); // 4*(N+1)
    int*      gcur    = row_ptr + 4 * NP1 + 60;       // 4*NBUK
    int*      srtbase = gcur + 4 * NBUK;              // 4*NBUK
    float*    M       = (float*)(srtbase + 4 * NBUK + 32);       // 4096 f
    unsigned long long* bucketed =
        (unsigned long long*)(M + HDIM * HDIM + 64);             // 4*NBUK*BCAP u64 = 32.1MB
    // y aliases bucketed: y live only in stage 1 (after build A, before build B).
    f16* y = (f16*)bucketed;                          // 4*NH halfs = 25.6MB < 32.1MB
    // W fragment tables after bucketed: 81920 f16 = 160KB
    f16* wfrag = (f16*)(bucketed + (size_t)4 * NBUK * BCAP);
    f16* wf1 = wfrag;            // 32768 f16
    f16* wf2 = wfrag + 32768;    // 16384 f16
    f16* wf3 = wfrag + 49152;    // 16384 f16
    f16* wf4 = wfrag + 65536;    // 16384 f16
    // total ~= 24.3M floats ~= 97.5 MB

    const int* r2 = adj_rows + 4 * (size_t)E_ADJ;
    const int* c2 = adj_cols + 4 * (size_t)E_ADJ;
    const float* v2 = adj_vals + 4 * (size_t)E_ADJ;

    // ---- pre-pack W fragments ----
    pack_wfrag<<<128, 256, 0, stream>>>(W1, FDIM, wf1);
    pack_wfrag<<<64, 256, 0, stream>>>(W2, HDIM, wf2);
    pack_wfrag<<<64, 256, 0, stream>>>(W3, HDIM, wf3);
    pack_wfrag<<<64, 256, 0, stream>>>(W4, HDIM, wf4);

    // ---- CSR for adjacency group A (stages 1 & 2) ----
    build_csr(adj_rows, adj_cols, adj_vals, gcur, srtbase, bucketed, srt, row_ptr, stream);

    // ---- stage 1: transform (MFMA) then aggregate ----
    gemm1_mfma<<<1563, 256, 0, stream>>>(feat0, feat1, wf1, xwh);
    spmm_csr<<<N_NODES, 256, 0, stream>>>(srt, row_ptr, xwh, y);
    combine_kernel<<<(int)(NH / 2 / 256), 256, 0, stream>>>(y, h0, h1);

    // ---- stage 2: aggregate then transform (MFMA) ----
    agg_csr<<<N_NODES, 256, 0, stream>>>(srt, row_ptr, h0, h1, xwh);
    gemm2_mfma<<<1563, 256, 0, stream>>>(xwh, wf2, h0, h1);

    // ---- CSR for adjacency group B (stages 3 & 4) ----
    build_csr(r2, c2, v2, gcur, srtbase, bucketed, srt, row_ptr, stream);

    // ---- stage 3 ----
    agg_csr<<<N_NODES, 256, 0, stream>>>(srt, row_ptr, h0, h1, xwh);
    gemm2_mfma<<<1563, 256, 0, stream>>>(xwh, wf3, h0, h1);

    // ---- stage 4 ----
    agg_csr<<<N_NODES, 256, 0, stream>>>(srt, row_ptr, h0, h1, xwh);
    gemm2_mfma<<<1563, 256, 0, stream>>>(xwh, wf4, h0, h1);

    // ---- decode: M, A = h0@M (fp16, aliases xwh), dot per edge ----
    make_M<<<(HDIM * HDIM + 255) / 256, 256, 0, stream>>>(Rg, Dl, rt_k, M);
    f16* A = xwh;
    h0M_kernel<<<N_NODES / 16, 256, 0, stream>>>(h0, M, A);
    decode<<<E_DEC * 16 / 256, 256, 0, stream>>>(A, h1, edges, out);
}

// Round 18
// 540.845 us; speedup vs baseline: 6.1041x; 1.0008x over previous
//
#include <hip/hip_runtime.h>

#define N_NODES 50000
#define E_ADJ   800000
#define E_DEC   200000
#define FDIM    128
#define HDIM    64
#define NP1     (N_NODES + 1)
#define NBUK    196            // ceil(50000/256) buckets of 256 rows
#define SCAP    768            // per-sub capacity (mean 510, +11 sigma)
#define BCAP    (8 * SCAP)     // 6144 per bucket
#define TILE_E  4096           // edges per part-block
#define EPB     16             // edges per thread
#define NPBLK   196            // ceil(E_ADJ/TILE_E)

typedef _Float16 f16;
typedef __attribute__((ext_vector_type(2))) _Float16 f16x2;
typedef __attribute__((ext_vector_type(4))) _Float16 f16x4;
typedef __attribute__((ext_vector_type(8))) _Float16 f16x8;
typedef __attribute__((ext_vector_type(4))) float f32x4;

__device__ __forceinline__ int   ntl_i(const int* p)   { return __builtin_nontemporal_load(p); }
__device__ __forceinline__ float ntl_f(const float* p) { return __builtin_nontemporal_load(p); }

// ---------------------------------------------------------------------------
// CSR build, two-level bucket sort. R17: gcur split 8 ways by blockIdx&7
// (XCD-aligned) -> same-address atomic chain 196 -> ~25 deep, L2-local.
// (R16 counters: part VALUBusy 2.8%, nothing busy; 196-chain x 300ns = 59us
// matched the 70us measured -> serialization, not bandwidth.)
// ---------------------------------------------------------------------------
__global__ void part_kernel(const int* __restrict__ rows,
                            const int* __restrict__ cols,
                            const float* __restrict__ vals,
                            int* __restrict__ gcur,            // [4][NBUK][8]
                            unsigned long long* __restrict__ bucketed)
{
    const int k   = blockIdx.y;
    const int sub = blockIdx.x & 7;
    const int tid = threadIdx.x;
    const long long t0 = (long long)blockIdx.x * TILE_E;

    __shared__ int hist[NBUK];
    __shared__ int sbase[NBUK];
    for (int i = tid; i < NBUK; i += 256) hist[i] = 0;
    __syncthreads();

    int lidx[EPB];
    int brl[EPB];                       // packed (bucket<<8)|row_local
#pragma unroll
    for (int it = 0; it < EPB; ++it) {
        const long long e = t0 + it * 256 + tid;
        brl[it] = -1;
        if (e < E_ADJ) {
            const int r = ntl_i(&rows[(size_t)k * E_ADJ + e]);
            const int b = r >> 8;
            brl[it] = (b << 8) | (r & 255);
            lidx[it] = atomicAdd(&hist[b], 1);      // LDS atomic
        }
    }
    __syncthreads();

    for (int i = tid; i < NBUK; i += 256)
        sbase[i] = (hist[i] > 0) ? atomicAdd(&gcur[(k * NBUK + i) * 8 + sub], hist[i]) : 0;
    __syncthreads();

#pragma unroll
    for (int it = 0; it < EPB; ++it) {
        if (brl[it] >= 0) {
            const long long e = t0 + it * 256 + tid;
            const int b  = brl[it] >> 8;
            const int rl = brl[it] & 255;
            const int c  = ntl_i(&cols[(size_t)k * E_ADJ + e]);
            const float v = ntl_f(&vals[(size_t)k * E_ADJ + e]);
            const unsigned meta = (unsigned)c | ((unsigned)rl << 16);   // col < 65536
            const unsigned long long payload =
                ((unsigned long long)__float_as_uint(v) << 32) | meta;
            bucketed[(size_t)(k * NBUK + b) * BCAP + sub * SCAP + sbase[b] + lidx[it]] = payload;
        }
    }
}

// Sum the 8 subs per bucket (parallel), then 4 serial scans over LDS.
__global__ void bucket_scan(const int* __restrict__ gcur, int* __restrict__ srtbase)
{
    __shared__ int tot[4 * NBUK];
    for (int i = threadIdx.x; i < 4 * NBUK; i += 256) {
        int t = 0;
#pragma unroll
        for (int s8 = 0; s8 < 8; ++s8) t += gcur[i * 8 + s8];
        tot[i] = t;
    }
    __syncthreads();
    if (threadIdx.x < 4) {
        const int k = threadIdx.x;
        int run = 0;
        for (int b = 0; b < NBUK; ++b) {
            srtbase[k * NBUK + b] = run;
            run += tot[k * NBUK + b];
        }
    }
}

// srt entry: {val_f16 << 16 | col_u16}.
__global__ void bucket_sort(const unsigned long long* __restrict__ bucketed,
                            const int* __restrict__ gcur,      // [4][NBUK][8]
                            const int* __restrict__ srtbase,
                            unsigned* __restrict__ srt,
                            int* __restrict__ row_ptr)
{
    const int b = blockIdx.x, k = blockIdx.y, tid = threadIdx.x;
    const int base = srtbase[k * NBUK + b];
    const unsigned long long* bk = bucketed + (size_t)(k * NBUK + b) * BCAP;

    __shared__ int scnt[8];
    __shared__ int s[256];
    __shared__ int cur[256];
    __shared__ int rcnt[256];
    rcnt[tid] = 0;
    if (tid < 8) scnt[tid] = gcur[(k * NBUK + b) * 8 + tid];
    __syncthreads();

    for (int s8 = 0; s8 < 8; ++s8) {
        const int c8 = scnt[s8];
        for (int i = tid; i < c8; i += 256) {
            const unsigned meta = (unsigned)bk[s8 * SCAP + i];
            atomicAdd(&rcnt[(meta >> 16) & 255], 1);
        }
    }
    __syncthreads();

    const int v = rcnt[tid];
    s[tid] = v;
    __syncthreads();
    for (int off = 1; off < 256; off <<= 1) {
        const int t = (tid >= off) ? s[tid - off] : 0;
        __syncthreads();
        s[tid] += t;
        __syncthreads();
    }
    const int excl = s[tid] - v;

    const int n = b * 256 + tid;
    if (n < N_NODES) row_ptr[k * NP1 + n] = base + excl;
    if (b == NBUK - 1 && tid == 0) row_ptr[k * NP1 + N_NODES] = E_ADJ;
    cur[tid] = base + excl;
    __syncthreads();

    for (int s8 = 0; s8 < 8; ++s8) {
        const int c8 = scnt[s8];
        for (int i = tid; i < c8; i += 256) {
            const unsigned long long p = bk[s8 * SCAP + i];
            const unsigned meta = (unsigned)p;
            const int rl = (meta >> 16) & 255;
            const int c  = meta & 0xFFFF;
            const float val = __uint_as_float((unsigned)(p >> 32));
            union { f16 h; unsigned short us; } cv;
            cv.h = (f16)val;
            const int pos = atomicAdd(&cur[rl], 1);
            srt[(size_t)k * E_ADJ + pos] = ((unsigned)cv.us << 16) | (unsigned)c;
        }
    }
}

// ---------------------------------------------------------------------------
// f16x4 quad gather core (R16, unchanged). Result valid on lanes 0-15.
// ---------------------------------------------------------------------------
__device__ __forceinline__ void gather_quads(const unsigned* __restrict__ sp,
                                             int s, int en,
                                             const f16* __restrict__ xk,
                                             int lane, float a[4])
{
    const int es = lane >> 4;
    const int hb = (lane & 15) * 4;

    for (int base = s; base < en; base += 64) {
        const int cnt = min(64, en - base);
        unsigned meta = 0;
        if (lane < cnt) meta = sp[base + lane];
        const int nq = (cnt + 3) >> 2;
        int p = 0;
        for (; p + 4 <= nq; p += 4) {
            unsigned m[4];
#pragma unroll
            for (int u = 0; u < 4; ++u)
                m[u] = __shfl(meta, (p + u) * 4 + es, 64);
            f16x4 g[4];
            float v[4];
#pragma unroll
            for (int u = 0; u < 4; ++u) {
                union { unsigned short us; f16 h; } cv;
                cv.us = (unsigned short)(m[u] >> 16);
                v[u] = (float)cv.h;
                g[u] = *(const f16x4*)(xk + (size_t)(m[u] & 0xFFFF) * HDIM + hb);
            }
#pragma unroll
            for (int u = 0; u < 4; ++u) {
                a[0] = fmaf((float)g[u][0], v[u], a[0]);
                a[1] = fmaf((float)g[u][1], v[u], a[1]);
                a[2] = fmaf((float)g[u][2], v[u], a[2]);
                a[3] = fmaf((float)g[u][3], v[u], a[3]);
            }
        }
        for (; p < nq; ++p) {
            const unsigned m = __shfl(meta, p * 4 + es, 64);
            union { unsigned short us; f16 h; } cv;
            cv.us = (unsigned short)(m >> 16);
            const float v = (float)cv.h;
            const f16x4 g = *(const f16x4*)(xk + (size_t)(m & 0xFFFF) * HDIM + hb);
            a[0] = fmaf((float)g[0], v, a[0]);
            a[1] = fmaf((float)g[1], v, a[1]);
            a[2] = fmaf((float)g[2], v, a[2]);
            a[3] = fmaf((float)g[3], v, a[3]);
        }
    }
#pragma unroll
    for (int j = 0; j < 4; ++j) {
        a[j] += __shfl_xor(a[j], 16, 64);
        a[j] += __shfl_xor(a[j], 32, 64);
    }
}

// ---------------------------------------------------------------------------
// W fragment pre-pack for mfma_f32_16x16x32_f16 (R15, unchanged).
// ---------------------------------------------------------------------------
__global__ void pack_wfrag(const float* __restrict__ W, const int K,
                           f16* __restrict__ out)
{
    const int idx = blockIdx.x * 256 + threadIdx.x;
    const int j    = idx & 7;
    const int lane = (idx >> 3) & 63;
    const int kcs  = K >> 5;
    int rest = idx >> 9;
    const int kc  = rest % kcs; rest /= kcs;
    const int nt  = rest & 3;
    const int rel = rest >> 2;
    const int k   = kc * 32 + ((lane >> 4) * 8) + j;
    const int col = nt * 16 + (lane & 15);
    out[idx] = (f16)W[((size_t)rel * K + k) * HDIM + col];
}

// ---------------------------------------------------------------------------
// Stage-1 transform via MFMA (R15, unchanged).
// ---------------------------------------------------------------------------
__global__ void gemm1_mfma(const float* __restrict__ x0,
                           const float* __restrict__ x1,
                           const f16* __restrict__ wf,   // [4][4][4][64][8]
                           f16* __restrict__ xw)         // [4][N][64]
{
    const int wave = threadIdx.x >> 6;   // relation
    const int lane = threadIdx.x & 63;
    const int n0 = blockIdx.x * 32;      // 1563 blocks cover 50016 (guarded)
    const int q = lane >> 4, r16 = lane & 15;

    const float* xr = (wave & 1) ? x1 : x0;

    f16x8 b[4][4];
#pragma unroll
    for (int nt = 0; nt < 4; ++nt)
#pragma unroll
        for (int kc = 0; kc < 4; ++kc)
            b[nt][kc] = *(const f16x8*)(wf + (((size_t)(wave * 4 + nt) * 4 + kc) * 64 + lane) * 8);

    for (int t = 0; t < 2; ++t) {
        const int row = n0 + t * 16 + r16;
        const int rowc = row < N_NODES ? row : N_NODES - 1;
        f16x8 a[4];
#pragma unroll
        for (int kc = 0; kc < 4; ++kc) {
            const float4 lo = *(const float4*)(xr + (size_t)rowc * FDIM + kc * 32 + q * 8);
            const float4 hi = *(const float4*)(xr + (size_t)rowc * FDIM + kc * 32 + q * 8 + 4);
            f16x8 av;
            av[0] = (f16)lo.x; av[1] = (f16)lo.y; av[2] = (f16)lo.z; av[3] = (f16)lo.w;
            av[4] = (f16)hi.x; av[5] = (f16)hi.y; av[6] = (f16)hi.z; av[7] = (f16)hi.w;
            a[kc] = av;
        }
#pragma unroll
        for (int nt = 0; nt < 4; ++nt) {
            f32x4 acc = {0.f, 0.f, 0.f, 0.f};
#pragma unroll
            for (int kc = 0; kc < 4; ++kc)
                acc = __builtin_amdgcn_mfma_f32_16x16x32_f16(a[kc], b[nt][kc], acc, 0, 0, 0);
#pragma unroll
            for (int j = 0; j < 4; ++j) {
                const int n = n0 + t * 16 + q * 4 + j;
                if (n < N_NODES)
                    xw[((size_t)wave * N_NODES + n) * HDIM + nt * 16 + r16] = (f16)acc[j];
            }
        }
    }
}

// ---------------------------------------------------------------------------
// Stages 2-4 transform via MFMA + fused relu + pairwise combine (R15).
// ---------------------------------------------------------------------------
__global__ void gemm2_mfma(const f16* __restrict__ agg,  // [4][N][64]
                           const f16* __restrict__ wf,   // [4][4][2][64][8]
                           f16* __restrict__ h0, f16* __restrict__ h1)
{
    const int wave = threadIdx.x >> 6;
    const int lane = threadIdx.x & 63;
    const int tid  = threadIdx.x;
    const int n0 = blockIdx.x * 32;
    const int q = lane >> 4, r16 = lane & 15;

    f16x8 b[4][2];
#pragma unroll
    for (int nt = 0; nt < 4; ++nt)
#pragma unroll
        for (int kc = 0; kc < 2; ++kc)
            b[nt][kc] = *(const f16x8*)(wf + (((size_t)(wave * 4 + nt) * 2 + kc) * 64 + lane) * 8);

    __shared__ f16 yt[4][16][HDIM];

    for (int t = 0; t < 2; ++t) {
        const int row = n0 + t * 16 + r16;
        const int rowc = row < N_NODES ? row : N_NODES - 1;
        f16x8 a[2];
#pragma unroll
        for (int kc = 0; kc < 2; ++kc)
            a[kc] = *(const f16x8*)(agg + ((size_t)wave * N_NODES + rowc) * HDIM + kc * 32 + q * 8);

#pragma unroll
        for (int nt = 0; nt < 4; ++nt) {
            f32x4 acc = {0.f, 0.f, 0.f, 0.f};
#pragma unroll
            for (int kc = 0; kc < 2; ++kc)
                acc = __builtin_amdgcn_mfma_f32_16x16x32_f16(a[kc], b[nt][kc], acc, 0, 0, 0);
#pragma unroll
            for (int j = 0; j < 4; ++j)
                yt[wave][q * 4 + j][nt * 16 + r16] = (f16)fmaxf(acc[j], 0.f);
        }
        __syncthreads();

        {
            const int r  = tid >> 4;          // 0..15
            const int c4 = (tid & 15) * 4;    // 0..60
            const int n  = n0 + t * 16 + r;
            if (n < N_NODES) {
                const f16x4 a0 = *(const f16x4*)&yt[0][r][c4];
                const f16x4 a1 = *(const f16x4*)&yt[1][r][c4];
                const f16x4 a2 = *(const f16x4*)&yt[2][r][c4];
                const f16x4 a3 = *(const f16x4*)&yt[3][r][c4];
                f16x4 o0, o1;
#pragma unroll
                for (int u = 0; u < 4; ++u) {
                    o0[u] = (f16)((float)a0[u] + (float)a1[u]);
                    o1[u] = (f16)((float)a2[u] + (float)a3[u]);
                }
                *(f16x4*)(h0 + (size_t)n * HDIM + c4) = o0;
                *(f16x4*)(h1 + (size_t)n * HDIM + c4) = o1;
            }
        }
        __syncthreads();
    }
}

// ---------------------------------------------------------------------------
// Stage-1 SPMM, relation-per-block + quad gathers (R16, unchanged).
// ---------------------------------------------------------------------------
__global__ void spmm_csr(const unsigned* __restrict__ srt,
                         const int*    __restrict__ row_ptr,
                         const f16*    __restrict__ xw,     // [4][N][H]
                         f16* __restrict__ y)               // [4][N][H] relu'd
{
    const int b = blockIdx.x, k = b & 3, g = b >> 2;        // 50000 blocks
    const int wave = threadIdx.x >> 6, lane = threadIdx.x & 63;
    const int n = g * 4 + wave;

    const int s  = row_ptr[k * NP1 + n];
    const int en = row_ptr[k * NP1 + n + 1];
    float a[4] = {0.f, 0.f, 0.f, 0.f};
    gather_quads(srt + (size_t)k * E_ADJ, s, en,
                 xw + (size_t)k * N_NODES * HDIM, lane, a);
    if (lane < 16) {
        f16x4 o;
        o[0] = (f16)fmaxf(a[0], 0.f);
        o[1] = (f16)fmaxf(a[1], 0.f);
        o[2] = (f16)fmaxf(a[2], 0.f);
        o[3] = (f16)fmaxf(a[3], 0.f);
        *(f16x4*)(y + ((size_t)k * N_NODES + n) * HDIM + lane * 4) = o;
    }
}

// h0 = y0+y1, h1 = y2+y3 (y already relu'd per relation).
__global__ void combine_kernel(const f16* __restrict__ y,
                               f16* __restrict__ h0, f16* __restrict__ h1)
{
    const size_t NHh = (size_t)N_NODES * HDIM / 2;
    const size_t i = (size_t)blockIdx.x * 256 + threadIdx.x;   // 6250 blocks exact
    const f16x2 a = ((const f16x2*)y)[i];
    const f16x2 b = ((const f16x2*)y)[NHh + i];
    const f16x2 c = ((const f16x2*)y)[2 * NHh + i];
    const f16x2 d = ((const f16x2*)y)[3 * NHh + i];
    f16x2 o0, o1;
    o0.x = (f16)((float)a.x + (float)b.x);
    o0.y = (f16)((float)a.y + (float)b.y);
    o1.x = (f16)((float)c.x + (float)d.x);
    o1.y = (f16)((float)c.y + (float)d.y);
    ((f16x2*)h0)[i] = o0;
    ((f16x2*)h1)[i] = o1;
}

// ---------------------------------------------------------------------------
// Stages 2-4 aggregate, relation-per-block + quad gathers (R16, unchanged).
// ---------------------------------------------------------------------------
__global__ void agg_csr(const unsigned* __restrict__ srt,
                        const int*    __restrict__ row_ptr,
                        const f16*    __restrict__ h0,
                        const f16*    __restrict__ h1,
                        f16* __restrict__ agg)    // [4][N][H]
{
    const int b = blockIdx.x, k = b & 3, g = b >> 2;        // 50000 blocks
    const int wave = threadIdx.x >> 6, lane = threadIdx.x & 63;
    const int n = g * 4 + wave;

    const int s  = row_ptr[k * NP1 + n];
    const int en = row_ptr[k * NP1 + n + 1];
    const f16* xk = (k & 1) ? h1 : h0;
    float a[4] = {0.f, 0.f, 0.f, 0.f};
    gather_quads(srt + (size_t)k * E_ADJ, s, en, xk, lane, a);
    if (lane < 16) {
        f16x4 o;
        o[0] = (f16)a[0];
        o[1] = (f16)a[1];
        o[2] = (f16)a[2];
        o[3] = (f16)a[3];
        *(f16x4*)(agg + ((size_t)k * N_NODES + n) * HDIM + lane * 4) = o;
    }
}

// ---------------------------------------------------------------------------
__global__ void make_M(const float* __restrict__ R, const float* __restrict__ Dl,
                       const int* __restrict__ rt_k, float* __restrict__ M)
{
    const int i = blockIdx.x * blockDim.x + threadIdx.x;
    if (i >= HDIM * HDIM) return;
    const float* d = Dl + rt_k[0] * HDIM;
    M[i] = d[i >> 6] * R[i] * d[i & 63];
}

// A[n][g] = sum_h h0[n][h] * M[h][g]   (fp16 out)
__global__ void h0M_kernel(const f16* __restrict__ h0, const float* __restrict__ M,
                           f16* __restrict__ A)
{
    const int wave = threadIdx.x >> 6, lane = threadIdx.x & 63;
    const int n0 = blockIdx.x * 16;      // 3125 blocks

    __shared__ float sx[16][HDIM];
    for (int i = threadIdx.x; i < 16 * HDIM; i += 256)
        sx[i >> 6][i & 63] = (float)h0[(size_t)n0 * HDIM + i];
    __syncthreads();

    float acc[4] = {0.f, 0.f, 0.f, 0.f};
#pragma unroll 4
    for (int f = 0; f < HDIM; ++f) {
        const float w = M[f * HDIM + lane];
#pragma unroll
        for (int r = 0; r < 4; ++r)
            acc[r] = fmaf(sx[wave * 4 + r][f], w, acc[r]);
    }
#pragma unroll
    for (int r = 0; r < 4; ++r)
        A[(size_t)(n0 + wave * 4 + r) * HDIM + lane] = (f16)acc[r];
}

// preds[e] = dot(A[i], h1[j]) — 4 edges/wave, f16x4 (8B) loads (R16).
__global__ void decode(const f16* __restrict__ A, const f16* __restrict__ h1,
                       const int* __restrict__ edges, float* __restrict__ out)
{
    const int w = (blockIdx.x * 256 + threadIdx.x) >> 6;   // 12500 blocks -> 50000 waves
    const int lane = threadIdx.x & 63;
    const int e = w * 4 + (lane >> 4);                     // 4 edges per wave
    const int q = lane & 15;

    const int i = edges[2 * (size_t)e];
    const int j = edges[2 * (size_t)e + 1];

    const f16x4 a = *(const f16x4*)(A + (size_t)i * HDIM + q * 4);
    const f16x4 b = *(const f16x4*)(h1 + (size_t)j * HDIM + q * 4);
    float p = 0.f;
#pragma unroll
    for (int u = 0; u < 4; ++u)
        p = fmaf((float)a[u], (float)b[u], p);
    p += __shfl_xor(p, 1, 64);
    p += __shfl_xor(p, 2, 64);
    p += __shfl_xor(p, 4, 64);
    p += __shfl_xor(p, 8, 64);
    if (q == 0) out[e] = p;
}

// ---------------------------------------------------------------------------
static void build_csr(const int* rows, const int* cols, const float* vals,
                      int* gcur, int* srtbase, unsigned long long* bucketed,
                      unsigned* srt, int* row_ptr, hipStream_t stream)
{
    hipMemsetAsync(gcur, 0, 4 * NBUK * 8 * sizeof(int), stream);
    part_kernel<<<dim3(NPBLK, 4), 256, 0, stream>>>(rows, cols, vals, gcur, bucketed);
    bucket_scan<<<1, 256, 0, stream>>>(gcur, srtbase);
    bucket_sort<<<dim3(NBUK, 4), 256, 0, stream>>>(bucketed, gcur, srtbase, srt, row_ptr);
}

extern "C" void kernel_launch(void* const* d_in, const int* in_sizes, int n_in,
                              void* d_out, int out_size, void* d_ws, size_t ws_size,
                              hipStream_t stream) {
    const int*   adj_rows = (const int*)  d_in[0];
    const int*   adj_cols = (const int*)  d_in[1];
    const float* adj_vals = (const float*)d_in[2];
    const float* feat0    = (const float*)d_in[3];
    const float* feat1    = (const float*)d_in[4];
    const float* W1       = (const float*)d_in[5];
    const float* W2       = (const float*)d_in[6];
    const float* W3       = (const float*)d_in[7];
    const float* W4       = (const float*)d_in[8];
    const float* Rg       = (const float*)d_in[9];
    const float* Dl       = (const float*)d_in[10];
    const int*   edges    = (const int*)  d_in[11];
    const int*   rt_k     = (const int*)  d_in[12];
    float* out = (float*)d_out;

    const size_t NH = (size_t)N_NODES * HDIM;       // 3.2M
    float* ws = (float*)d_ws;
    // layout (float offsets):
    f16*      xwh     = (f16*)ws;                     // 4*NH halfs (table / agg / A)
    f16*      h0      = (f16*)(ws + 2 * NH);          // NH halfs
    f16*      h1      = (f16*)(ws + 2 * NH + NH / 2); // NH halfs
    unsigned* srt     = (unsigned*)(ws + 3 * NH);     // 4E u32 (12.8MB)
    int*      row_ptr = (int*)(ws + 3 * NH + 8 * (size_t)E_ADJ); // 4*(N+1)
    int*      gcur    = row_ptr + 4 * NP1 + 60;       // 4*NBUK*8
    int*      srtbase = gcur + 4 * NBUK * 8;          // 4*NBUK
    float*    M       = (float*)(srtbase + 4 * NBUK + 32);       // 4096 f
    unsigned long long* bucketed =
        (unsigned long long*)(M + HDIM * HDIM + 64);             // 4*NBUK*BCAP u64 = 38.5MB
    // y aliases bucketed: y live only in stage 1 (after build A, before build B).
    f16* y = (f16*)bucketed;                          // 4*NH halfs = 25.6MB < 38.5MB
    // W fragment tables after bucketed: 81920 f16 = 160KB
    f16* wfrag = (f16*)(bucketed + (size_t)4 * NBUK * BCAP);
    f16* wf1 = wfrag;            // 32768 f16
    f16* wf2 = wfrag + 32768;    // 16384 f16
    f16* wf3 = wfrag + 49152;    // 16384 f16
    f16* wf4 = wfrag + 65536;    // 16384 f16
    // total ~= 26M floats ~= 104 MB (<= R1's proven 128 MB)

    const int* r2 = adj_rows + 4 * (size_t)E_ADJ;
    const int* c2 = adj_cols + 4 * (size_t)E_ADJ;
    const float* v2 = adj_vals + 4 * (size_t)E_ADJ;

    // ---- pre-pack W fragments ----
    pack_wfrag<<<128, 256, 0, stream>>>(W1, FDIM, wf1);
    pack_wfrag<<<64, 256, 0, stream>>>(W2, HDIM, wf2);
    pack_wfrag<<<64, 256, 0, stream>>>(W3, HDIM, wf3);
    pack_wfrag<<<64, 256, 0, stream>>>(W4, HDIM, wf4);

    // ---- CSR for adjacency group A (stages 1 & 2) ----
    build_csr(adj_rows, adj_cols, adj_vals, gcur, srtbase, bucketed, srt, row_ptr, stream);

    // ---- stage 1: transform (MFMA) then aggregate ----
    gemm1_mfma<<<1563, 256, 0, stream>>>(feat0, feat1, wf1, xwh);
    spmm_csr<<<N_NODES, 256, 0, stream>>>(srt, row_ptr, xwh, y);
    combine_kernel<<<(int)(NH / 2 / 256), 256, 0, stream>>>(y, h0, h1);

    // ---- stage 2: aggregate then transform (MFMA) ----
    agg_csr<<<N_NODES, 256, 0, stream>>>(srt, row_ptr, h0, h1, xwh);
    gemm2_mfma<<<1563, 256, 0, stream>>>(xwh, wf2, h0, h1);

    // ---- CSR for adjacency group B (stages 3 & 4) ----
    build_csr(r2, c2, v2, gcur, srtbase, bucketed, srt, row_ptr, stream);

    // ---- stage 3 ----
    agg_csr<<<N_NODES, 256, 0, stream>>>(srt, row_ptr, h0, h1, xwh);
    gemm2_mfma<<<1563, 256, 0, stream>>>(xwh, wf3, h0, h1);

    // ---- stage 4 ----
    agg_csr<<<N_NODES, 256, 0, stream>>>(srt, row_ptr, h0, h1, xwh);
    gemm2_mfma<<<1563, 256, 0, stream>>>(xwh, wf4, h0, h1);

    // ---- decode: M, A = h0@M (fp16, aliases xwh), dot per edge ----
    make_M<<<(HDIM * HDIM + 255) / 256, 256, 0, stream>>>(Rg, Dl, rt_k, M);
    f16* A = xwh;
    h0M_kernel<<<N_NODES / 16, 256, 0, stream>>>(h0, M, A);
    decode<<<E_DEC * 16 / 256, 256, 0, stream>>>(A, h1, edges, out);
}

// Round 19
// 538.699 us; speedup vs baseline: 6.1284x; 1.0040x over previous
//
#include <hip/hip_runtime.h>

#define N_NODES 50000
#define E_ADJ   800000
#define E_DEC   200000
#define FDIM    128
#define HDIM    64
#define NP1     (N_NODES + 1)
#define NBUK    196            // ceil(50000/256) buckets of 256 rows
#define SCAP    768            // per-sub capacity (mean 510, +11 sigma)
#define BCAP    (8 * SCAP)     // 6144 per bucket
#define TILE_E  4096           // edges per part-block
#define EPB     16             // edges per thread
#define NPBLK   196            // ceil(E_ADJ/TILE_E)

typedef _Float16 f16;
typedef __attribute__((ext_vector_type(2))) _Float16 f16x2;
typedef __attribute__((ext_vector_type(4))) _Float16 f16x4;
typedef __attribute__((ext_vector_type(8))) _Float16 f16x8;
typedef __attribute__((ext_vector_type(4))) float f32x4;

__device__ __forceinline__ int   ntl_i(const int* p)   { return __builtin_nontemporal_load(p); }
__device__ __forceinline__ float ntl_f(const float* p) { return __builtin_nontemporal_load(p); }

// ---------------------------------------------------------------------------
// CSR build, two-level bucket sort. R19: two-pass part_kernel with ZERO
// per-thread arrays. (R18 post-mortem: VGPR_Count=24 < the 32 regs the
// lidx[16]/brl[16] arrays need -> they were scratch-spilled; WRITE_SIZE 82MB
// vs 25.6MB logical = scratch traffic; VALUBusy 2.8% = scratch stalls.)
// Pass 1 histograms rows; pass 2 RE-READS rows (L1/L2-hot, regular loads)
// and scatters. No saved per-edge state.
// ---------------------------------------------------------------------------
__global__ void part_kernel(const int* __restrict__ rows,
                            const int* __restrict__ cols,
                            const float* __restrict__ vals,
                            int* __restrict__ gcur,            // [4][NBUK][8]
                            unsigned long long* __restrict__ bucketed)
{
    const int k   = blockIdx.y;
    const int sub = blockIdx.x & 7;
    const int tid = threadIdx.x;
    const long long t0 = (long long)blockIdx.x * TILE_E;

    __shared__ int hist[NBUK];
    __shared__ int cur[NBUK];
    for (int i = tid; i < NBUK; i += 256) hist[i] = 0;
    __syncthreads();

    // pass 1: histogram (regular loads -> lines stay cached for pass 2)
    for (int it = 0; it < EPB; ++it) {
        const long long e = t0 + it * 256 + tid;
        if (e < E_ADJ) {
            const int r = rows[(size_t)k * E_ADJ + e];
            atomicAdd(&hist[r >> 8], 1);
        }
    }
    __syncthreads();

    // reserve per-(bucket,sub) ranges; cur[b] = running cursor
    for (int i = tid; i < NBUK; i += 256)
        cur[i] = (hist[i] > 0) ? atomicAdd(&gcur[(k * NBUK + i) * 8 + sub], hist[i]) : 0;
    __syncthreads();

    // pass 2: re-read rows (cache-hot), take slot, scatter payload
    for (int it = 0; it < EPB; ++it) {
        const long long e = t0 + it * 256 + tid;
        if (e < E_ADJ) {
            const int r = rows[(size_t)k * E_ADJ + e];
            const int b = r >> 8;
            const int pos = atomicAdd(&cur[b], 1);
            const int c = ntl_i(&cols[(size_t)k * E_ADJ + e]);
            const float v = ntl_f(&vals[(size_t)k * E_ADJ + e]);
            const unsigned meta = (unsigned)c | ((unsigned)(r & 255) << 16); // col < 65536
            const unsigned long long payload =
                ((unsigned long long)__float_as_uint(v) << 32) | meta;
            bucketed[(size_t)(k * NBUK + b) * BCAP + sub * SCAP + pos] = payload;
        }
    }
}

// Sum the 8 subs per bucket (parallel), then 4 serial scans over LDS.
__global__ void bucket_scan(const int* __restrict__ gcur, int* __restrict__ srtbase)
{
    __shared__ int tot[4 * NBUK];
    for (int i = threadIdx.x; i < 4 * NBUK; i += 256) {
        int t = 0;
#pragma unroll
        for (int s8 = 0; s8 < 8; ++s8) t += gcur[i * 8 + s8];
        tot[i] = t;
    }
    __syncthreads();
    if (threadIdx.x < 4) {
        const int k = threadIdx.x;
        int run = 0;
        for (int b = 0; b < NBUK; ++b) {
            srtbase[k * NBUK + b] = run;
            run += tot[k * NBUK + b];
        }
    }
}

// srt entry: {val_f16 << 16 | col_u16}.
__global__ void bucket_sort(const unsigned long long* __restrict__ bucketed,
                            const int* __restrict__ gcur,      // [4][NBUK][8]
                            const int* __restrict__ srtbase,
                            unsigned* __restrict__ srt,
                            int* __restrict__ row_ptr)
{
    const int b = blockIdx.x, k = blockIdx.y, tid = threadIdx.x;
    const int base = srtbase[k * NBUK + b];
    const unsigned long long* bk = bucketed + (size_t)(k * NBUK + b) * BCAP;

    __shared__ int scnt[8];
    __shared__ int s[256];
    __shared__ int cur[256];
    __shared__ int rcnt[256];
    rcnt[tid] = 0;
    if (tid < 8) scnt[tid] = gcur[(k * NBUK + b) * 8 + tid];
    __syncthreads();

    for (int s8 = 0; s8 < 8; ++s8) {
        const int c8 = scnt[s8];
        for (int i = tid; i < c8; i += 256) {
            const unsigned meta = (unsigned)bk[s8 * SCAP + i];
            atomicAdd(&rcnt[(meta >> 16) & 255], 1);
        }
    }
    __syncthreads();

    const int v = rcnt[tid];
    s[tid] = v;
    __syncthreads();
    for (int off = 1; off < 256; off <<= 1) {
        const int t = (tid >= off) ? s[tid - off] : 0;
        __syncthreads();
        s[tid] += t;
        __syncthreads();
    }
    const int excl = s[tid] - v;

    const int n = b * 256 + tid;
    if (n < N_NODES) row_ptr[k * NP1 + n] = base + excl;
    if (b == NBUK - 1 && tid == 0) row_ptr[k * NP1 + N_NODES] = E_ADJ;
    cur[tid] = base + excl;
    __syncthreads();

    for (int s8 = 0; s8 < 8; ++s8) {
        const int c8 = scnt[s8];
        for (int i = tid; i < c8; i += 256) {
            const unsigned long long p = bk[s8 * SCAP + i];
            const unsigned meta = (unsigned)p;
            const int rl = (meta >> 16) & 255;
            const int c  = meta & 0xFFFF;
            const float val = __uint_as_float((unsigned)(p >> 32));
            union { f16 h; unsigned short us; } cv;
            cv.h = (f16)val;
            const int pos = atomicAdd(&cur[rl], 1);
            srt[(size_t)k * E_ADJ + pos] = ((unsigned)cv.us << 16) | (unsigned)c;
        }
    }
}

// ---------------------------------------------------------------------------
// f16x4 quad gather core (R16, unchanged). Result valid on lanes 0-15.
// ---------------------------------------------------------------------------
__device__ __forceinline__ void gather_quads(const unsigned* __restrict__ sp,
                                             int s, int en,
                                             const f16* __restrict__ xk,
                                             int lane, float a[4])
{
    const int es = lane >> 4;
    const int hb = (lane & 15) * 4;

    for (int base = s; base < en; base += 64) {
        const int cnt = min(64, en - base);
        unsigned meta = 0;
        if (lane < cnt) meta = sp[base + lane];
        const int nq = (cnt + 3) >> 2;
        int p = 0;
        for (; p + 4 <= nq; p += 4) {
            unsigned m[4];
#pragma unroll
            for (int u = 0; u < 4; ++u)
                m[u] = __shfl(meta, (p + u) * 4 + es, 64);
            f16x4 g[4];
            float v[4];
#pragma unroll
            for (int u = 0; u < 4; ++u) {
                union { unsigned short us; f16 h; } cv;
                cv.us = (unsigned short)(m[u] >> 16);
                v[u] = (float)cv.h;
                g[u] = *(const f16x4*)(xk + (size_t)(m[u] & 0xFFFF) * HDIM + hb);
            }
#pragma unroll
            for (int u = 0; u < 4; ++u) {
                a[0] = fmaf((float)g[u][0], v[u], a[0]);
                a[1] = fmaf((float)g[u][1], v[u], a[1]);
                a[2] = fmaf((float)g[u][2], v[u], a[2]);
                a[3] = fmaf((float)g[u][3], v[u], a[3]);
            }
        }
        for (; p < nq; ++p) {
            const unsigned m = __shfl(meta, p * 4 + es, 64);
            union { unsigned short us; f16 h; } cv;
            cv.us = (unsigned short)(m >> 16);
            const float v = (float)cv.h;
            const f16x4 g = *(const f16x4*)(xk + (size_t)(m & 0xFFFF) * HDIM + hb);
            a[0] = fmaf((float)g[0], v, a[0]);
            a[1] = fmaf((float)g[1], v, a[1]);
            a[2] = fmaf((float)g[2], v, a[2]);
            a[3] = fmaf((float)g[3], v, a[3]);
        }
    }
#pragma unroll
    for (int j = 0; j < 4; ++j) {
        a[j] += __shfl_xor(a[j], 16, 64);
        a[j] += __shfl_xor(a[j], 32, 64);
    }
}

// ---------------------------------------------------------------------------
// W fragment pre-pack for mfma_f32_16x16x32_f16 (R15, unchanged).
// ---------------------------------------------------------------------------
__global__ void pack_wfrag(const float* __restrict__ W, const int K,
                           f16* __restrict__ out)
{
    const int idx = blockIdx.x * 256 + threadIdx.x;
    const int j    = idx & 7;
    const int lane = (idx >> 3) & 63;
    const int kcs  = K >> 5;
    int rest = idx >> 9;
    const int kc  = rest % kcs; rest /= kcs;
    const int nt  = rest & 3;
    const int rel = rest >> 2;
    const int k   = kc * 32 + ((lane >> 4) * 8) + j;
    const int col = nt * 16 + (lane & 15);
    out[idx] = (f16)W[((size_t)rel * K + k) * HDIM + col];
}

// ---------------------------------------------------------------------------
// Stage-1 transform via MFMA (R15, unchanged).
// ---------------------------------------------------------------------------
__global__ void gemm1_mfma(const float* __restrict__ x0,
                           const float* __restrict__ x1,
                           const f16* __restrict__ wf,   // [4][4][4][64][8]
                           f16* __restrict__ xw)         // [4][N][64]
{
    const int wave = threadIdx.x >> 6;   // relation
    const int lane = threadIdx.x & 63;
    const int n0 = blockIdx.x * 32;      // 1563 blocks cover 50016 (guarded)
    const int q = lane >> 4, r16 = lane & 15;

    const float* xr = (wave & 1) ? x1 : x0;

    f16x8 b[4][4];
#pragma unroll
    for (int nt = 0; nt < 4; ++nt)
#pragma unroll
        for (int kc = 0; kc < 4; ++kc)
            b[nt][kc] = *(const f16x8*)(wf + (((size_t)(wave * 4 + nt) * 4 + kc) * 64 + lane) * 8);

    for (int t = 0; t < 2; ++t) {
        const int row = n0 + t * 16 + r16;
        const int rowc = row < N_NODES ? row : N_NODES - 1;
        f16x8 a[4];
#pragma unroll
        for (int kc = 0; kc < 4; ++kc) {
            const float4 lo = *(const float4*)(xr + (size_t)rowc * FDIM + kc * 32 + q * 8);
            const float4 hi = *(const float4*)(xr + (size_t)rowc * FDIM + kc * 32 + q * 8 + 4);
            f16x8 av;
            av[0] = (f16)lo.x; av[1] = (f16)lo.y; av[2] = (f16)lo.z; av[3] = (f16)lo.w;
            av[4] = (f16)hi.x; av[5] = (f16)hi.y; av[6] = (f16)hi.z; av[7] = (f16)hi.w;
            a[kc] = av;
        }
#pragma unroll
        for (int nt = 0; nt < 4; ++nt) {
            f32x4 acc = {0.f, 0.f, 0.f, 0.f};
#pragma unroll
            for (int kc = 0; kc < 4; ++kc)
                acc = __builtin_amdgcn_mfma_f32_16x16x32_f16(a[kc], b[nt][kc], acc, 0, 0, 0);
#pragma unroll
            for (int j = 0; j < 4; ++j) {
                const int n = n0 + t * 16 + q * 4 + j;
                if (n < N_NODES)
                    xw[((size_t)wave * N_NODES + n) * HDIM + nt * 16 + r16] = (f16)acc[j];
            }
        }
    }
}

// ---------------------------------------------------------------------------
// Stages 2-4 transform via MFMA + fused relu + pairwise combine (R15).
// ---------------------------------------------------------------------------
__global__ void gemm2_mfma(const f16* __restrict__ agg,  // [4][N][64]
                           const f16* __restrict__ wf,   // [4][4][2][64][8]
                           f16* __restrict__ h0, f16* __restrict__ h1)
{
    const int wave = threadIdx.x >> 6;
    const int lane = threadIdx.x & 63;
    const int tid  = threadIdx.x;
    const int n0 = blockIdx.x * 32;
    const int q = lane >> 4, r16 = lane & 15;

    f16x8 b[4][2];
#pragma unroll
    for (int nt = 0; nt < 4; ++nt)
#pragma unroll
        for (int kc = 0; kc < 2; ++kc)
            b[nt][kc] = *(const f16x8*)(wf + (((size_t)(wave * 4 + nt) * 2 + kc) * 64 + lane) * 8);

    __shared__ f16 yt[4][16][HDIM];

    for (int t = 0; t < 2; ++t) {
        const int row = n0 + t * 16 + r16;
        const int rowc = row < N_NODES ? row : N_NODES - 1;
        f16x8 a[2];
#pragma unroll
        for (int kc = 0; kc < 2; ++kc)
            a[kc] = *(const f16x8*)(agg + ((size_t)wave * N_NODES + rowc) * HDIM + kc * 32 + q * 8);

#pragma unroll
        for (int nt = 0; nt < 4; ++nt) {
            f32x4 acc = {0.f, 0.f, 0.f, 0.f};
#pragma unroll
            for (int kc = 0; kc < 2; ++kc)
                acc = __builtin_amdgcn_mfma_f32_16x16x32_f16(a[kc], b[nt][kc], acc, 0, 0, 0);
#pragma unroll
            for (int j = 0; j < 4; ++j)
                yt[wave][q * 4 + j][nt * 16 + r16] = (f16)fmaxf(acc[j], 0.f);
        }
        __syncthreads();

        {
            const int r  = tid >> 4;          // 0..15
            const int c4 = (tid & 15) * 4;    // 0..60
            const int n  = n0 + t * 16 + r;
            if (n < N_NODES) {
                const f16x4 a0 = *(const f16x4*)&yt[0][r][c4];
                const f16x4 a1 = *(const f16x4*)&yt[1][r][c4];
                const f16x4 a2 = *(const f16x4*)&yt[2][r][c4];
                const f16x4 a3 = *(const f16x4*)&yt[3][r][c4];
                f16x4 o0, o1;
#pragma unroll
                for (int u = 0; u < 4; ++u) {
                    o0[u] = (f16)((float)a0[u] + (float)a1[u]);
                    o1[u] = (f16)((float)a2[u] + (float)a3[u]);
                }
                *(f16x4*)(h0 + (size_t)n * HDIM + c4) = o0;
                *(f16x4*)(h1 + (size_t)n * HDIM + c4) = o1;
            }
        }
        __syncthreads();
    }
}

// ---------------------------------------------------------------------------
// Stage-1 SPMM, relation-per-block + quad gathers (R16, unchanged).
// ---------------------------------------------------------------------------
__global__ void spmm_csr(const unsigned* __restrict__ srt,
                         const int*    __restrict__ row_ptr,
                         const f16*    __restrict__ xw,     // [4][N][H]
                         f16* __restrict__ y)               // [4][N][H] relu'd
{
    const int b = blockIdx.x, k = b & 3, g = b >> 2;        // 50000 blocks
    const int wave = threadIdx.x >> 6, lane = threadIdx.x & 63;
    const int n = g * 4 + wave;

    const int s  = row_ptr[k * NP1 + n];
    const int en = row_ptr[k * NP1 + n + 1];
    float a[4] = {0.f, 0.f, 0.f, 0.f};
    gather_quads(srt + (size_t)k * E_ADJ, s, en,
                 xw + (size_t)k * N_NODES * HDIM, lane, a);
    if (lane < 16) {
        f16x4 o;
        o[0] = (f16)fmaxf(a[0], 0.f);
        o[1] = (f16)fmaxf(a[1], 0.f);
        o[2] = (f16)fmaxf(a[2], 0.f);
        o[3] = (f16)fmaxf(a[3], 0.f);
        *(f16x4*)(y + ((size_t)k * N_NODES + n) * HDIM + lane * 4) = o;
    }
}

// h0 = y0+y1, h1 = y2+y3 (y already relu'd per relation).
__global__ void combine_kernel(const f16* __restrict__ y,
                               f16* __restrict__ h0, f16* __restrict__ h1)
{
    const size_t NHh = (size_t)N_NODES * HDIM / 2;
    const size_t i = (size_t)blockIdx.x * 256 + threadIdx.x;   // 6250 blocks exact
    const f16x2 a = ((const f16x2*)y)[i];
    const f16x2 b = ((const f16x2*)y)[NHh + i];
    const f16x2 c = ((const f16x2*)y)[2 * NHh + i];
    const f16x2 d = ((const f16x2*)y)[3 * NHh + i];
    f16x2 o0, o1;
    o0.x = (f16)((float)a.x + (float)b.x);
    o0.y = (f16)((float)a.y + (float)b.y);
    o1.x = (f16)((float)c.x + (float)d.x);
    o1.y = (f16)((float)c.y + (float)d.y);
    ((f16x2*)h0)[i] = o0;
    ((f16x2*)h1)[i] = o1;
}

// ---------------------------------------------------------------------------
// Stages 2-4 aggregate, relation-per-block + quad gathers (R16, unchanged).
// ---------------------------------------------------------------------------
__global__ void agg_csr(const unsigned* __restrict__ srt,
                        const int*    __restrict__ row_ptr,
                        const f16*    __restrict__ h0,
                        const f16*    __restrict__ h1,
                        f16* __restrict__ agg)    // [4][N][H]
{
    const int b = blockIdx.x, k = b & 3, g = b >> 2;        // 50000 blocks
    const int wave = threadIdx.x >> 6, lane = threadIdx.x & 63;
    const int n = g * 4 + wave;

    const int s  = row_ptr[k * NP1 + n];
    const int en = row_ptr[k * NP1 + n + 1];
    const f16* xk = (k & 1) ? h1 : h0;
    float a[4] = {0.f, 0.f, 0.f, 0.f};
    gather_quads(srt + (size_t)k * E_ADJ, s, en, xk, lane, a);
    if (lane < 16) {
        f16x4 o;
        o[0] = (f16)a[0];
        o[1] = (f16)a[1];
        o[2] = (f16)a[2];
        o[3] = (f16)a[3];
        *(f16x4*)(agg + ((size_t)k * N_NODES + n) * HDIM + lane * 4) = o;
    }
}

// ---------------------------------------------------------------------------
__global__ void make_M(const float* __restrict__ R, const float* __restrict__ Dl,
                       const int* __restrict__ rt_k, float* __restrict__ M)
{
    const int i = blockIdx.x * blockDim.x + threadIdx.x;
    if (i >= HDIM * HDIM) return;
    const float* d = Dl + rt_k[0] * HDIM;
    M[i] = d[i >> 6] * R[i] * d[i & 63];
}

// A[n][g] = sum_h h0[n][h] * M[h][g]   (fp16 out)
__global__ void h0M_kernel(const f16* __restrict__ h0, const float* __restrict__ M,
                           f16* __restrict__ A)
{
    const int wave = threadIdx.x >> 6, lane = threadIdx.x & 63;
    const int n0 = blockIdx.x * 16;      // 3125 blocks

    __shared__ float sx[16][HDIM];
    for (int i = threadIdx.x; i < 16 * HDIM; i += 256)
        sx[i >> 6][i & 63] = (float)h0[(size_t)n0 * HDIM + i];
    __syncthreads();

    float acc[4] = {0.f, 0.f, 0.f, 0.f};
#pragma unroll 4
    for (int f = 0; f < HDIM; ++f) {
        const float w = M[f * HDIM + lane];
#pragma unroll
        for (int r = 0; r < 4; ++r)
            acc[r] = fmaf(sx[wave * 4 + r][f], w, acc[r]);
    }
#pragma unroll
    for (int r = 0; r < 4; ++r)
        A[(size_t)(n0 + wave * 4 + r) * HDIM + lane] = (f16)acc[r];
}

// preds[e] = dot(A[i], h1[j]) — 4 edges/wave, f16x4 (8B) loads (R16).
__global__ void decode(const f16* __restrict__ A, const f16* __restrict__ h1,
                       const int* __restrict__ edges, float* __restrict__ out)
{
    const int w = (blockIdx.x * 256 + threadIdx.x) >> 6;   // 12500 blocks -> 50000 waves
    const int lane = threadIdx.x & 63;
    const int e = w * 4 + (lane >> 4);                     // 4 edges per wave
    const int q = lane & 15;

    const int i = edges[2 * (size_t)e];
    const int j = edges[2 * (size_t)e + 1];

    const f16x4 a = *(const f16x4*)(A + (size_t)i * HDIM + q * 4);
    const f16x4 b = *(const f16x4*)(h1 + (size_t)j * HDIM + q * 4);
    float p = 0.f;
#pragma unroll
    for (int u = 0; u < 4; ++u)
        p = fmaf((float)a[u], (float)b[u], p);
    p += __shfl_xor(p, 1, 64);
    p += __shfl_xor(p, 2, 64);
    p += __shfl_xor(p, 4, 64);
    p += __shfl_xor(p, 8, 64);
    if (q == 0) out[e] = p;
}

// ---------------------------------------------------------------------------
static void build_csr(const int* rows, const int* cols, const float* vals,
                      int* gcur, int* srtbase, unsigned long long* bucketed,
                      unsigned* srt, int* row_ptr, hipStream_t stream)
{
    hipMemsetAsync(gcur, 0, 4 * NBUK * 8 * sizeof(int), stream);
    part_kernel<<<dim3(NPBLK, 4), 256, 0, stream>>>(rows, cols, vals, gcur, bucketed);
    bucket_scan<<<1, 256, 0, stream>>>(gcur, srtbase);
    bucket_sort<<<dim3(NBUK, 4), 256, 0, stream>>>(bucketed, gcur, srtbase, srt, row_ptr);
}

extern "C" void kernel_launch(void* const* d_in, const int* in_sizes, int n_in,
                              void* d_out, int out_size, void* d_ws, size_t ws_size,
                              hipStream_t stream) {
    const int*   adj_rows = (const int*)  d_in[0];
    const int*   adj_cols = (const int*)  d_in[1];
    const float* adj_vals = (const float*)d_in[2];
    const float* feat0    = (const float*)d_in[3];
    const float* feat1    = (const float*)d_in[4];
    const float* W1       = (const float*)d_in[5];
    const float* W2       = (const float*)d_in[6];
    const float* W3       = (const float*)d_in[7];
    const float* W4       = (const float*)d_in[8];
    const float* Rg       = (const float*)d_in[9];
    const float* Dl       = (const float*)d_in[10];
    const int*   edges    = (const int*)  d_in[11];
    const int*   rt_k     = (const int*)  d_in[12];
    float* out = (float*)d_out;

    const size_t NH = (size_t)N_NODES * HDIM;       // 3.2M
    float* ws = (float*)d_ws;
    // layout (float offsets):
    f16*      xwh     = (f16*)ws;                     // 4*NH halfs (table / agg / A)
    f16*      h0      = (f16*)(ws + 2 * NH);          // NH halfs
    f16*      h1      = (f16*)(ws + 2 * NH + NH / 2); // NH halfs
    unsigned* srt     = (unsigned*)(ws + 3 * NH);     // 4E u32 (12.8MB)
    int*      row_ptr = (int*)(ws + 3 * NH + 8 * (size_t)E_ADJ); // 4*(N+1)
    int*      gcur    = row_ptr + 4 * NP1 + 60;       // 4*NBUK*8
    int*      srtbase = gcur + 4 * NBUK * 8;          // 4*NBUK
    float*    M       = (float*)(srtbase + 4 * NBUK + 32);       // 4096 f
    unsigned long long* bucketed =
        (unsigned long long*)(M + HDIM * HDIM + 64);             // 4*NBUK*BCAP u64 = 38.5MB
    // y aliases bucketed: y live only in stage 1 (after build A, before build B).
    f16* y = (f16*)bucketed;                          // 4*NH halfs = 25.6MB < 38.5MB
    // W fragment tables after bucketed: 81920 f16 = 160KB
    f16* wfrag = (f16*)(bucketed + (size_t)4 * NBUK * BCAP);
    f16* wf1 = wfrag;            // 32768 f16
    f16* wf2 = wfrag + 32768;    // 16384 f16
    f16* wf3 = wfrag + 49152;    // 16384 f16
    f16* wf4 = wfrag + 65536;    // 16384 f16
    // total ~= 26M floats ~= 104 MB (<= R1's proven 128 MB)

    const int* r2 = adj_rows + 4 * (size_t)E_ADJ;
    const int* c2 = adj_cols + 4 * (size_t)E_ADJ;
    const float* v2 = adj_vals + 4 * (size_t)E_ADJ;

    // ---- pre-pack W fragments ----
    pack_wfrag<<<128, 256, 0, stream>>>(W1, FDIM, wf1);
    pack_wfrag<<<64, 256, 0, stream>>>(W2, HDIM, wf2);
    pack_wfrag<<<64, 256, 0, stream>>>(W3, HDIM, wf3);
    pack_wfrag<<<64, 256, 0, stream>>>(W4, HDIM, wf4);

    // ---- CSR for adjacency group A (stages 1 & 2) ----
    build_csr(adj_rows, adj_cols, adj_vals, gcur, srtbase, bucketed, srt, row_ptr, stream);

    // ---- stage 1: transform (MFMA) then aggregate ----
    gemm1_mfma<<<1563, 256, 0, stream>>>(feat0, feat1, wf1, xwh);
    spmm_csr<<<N_NODES, 256, 0, stream>>>(srt, row_ptr, xwh, y);
    combine_kernel<<<(int)(NH / 2 / 256), 256, 0, stream>>>(y, h0, h1);

    // ---- stage 2: aggregate then transform (MFMA) ----
    agg_csr<<<N_NODES, 256, 0, stream>>>(srt, row_ptr, h0, h1, xwh);
    gemm2_mfma<<<1563, 256, 0, stream>>>(xwh, wf2, h0, h1);

    // ---- CSR for adjacency group B (stages 3 & 4) ----
    build_csr(r2, c2, v2, gcur, srtbase, bucketed, srt, row_ptr, stream);

    // ---- stage 3 ----
    agg_csr<<<N_NODES, 256, 0, stream>>>(srt, row_ptr, h0, h1, xwh);
    gemm2_mfma<<<1563, 256, 0, stream>>>(xwh, wf3, h0, h1);

    // ---- stage 4 ----
    agg_csr<<<N_NODES, 256, 0, stream>>>(srt, row_ptr, h0, h1, xwh);
    gemm2_mfma<<<1563, 256, 0, stream>>>(xwh, wf4, h0, h1);

    // ---- decode: M, A = h0@M (fp16, aliases xwh), dot per edge ----
    make_M<<<(HDIM * HDIM + 255) / 256, 256, 0, stream>>>(Rg, Dl, rt_k, M);
    f16* A = xwh;
    h0M_kernel<<<N_NODES / 16, 256, 0, stream>>>(h0, M, A);
    decode<<<E_DEC * 16 / 256, 256, 0, stream>>>(A, h1, edges, out);
}